// Round 1
// baseline (1502.745 us; speedup 1.0000x reference)
//
#include <hip/hip_runtime.h>
#include <cstdint>
#include <cstddef>

constexpr int HID = 128;
constexpr int LATENT = 64;

// ---------------- degree counts ----------------
__global__ __launch_bounds__(256) void count_edges_k(const int* __restrict__ dst,
                                                     float* __restrict__ cnt, int nE) {
    int i = blockIdx.x * 256 + threadIdx.x;
    if (i < nE) unsafeAtomicAdd(&cnt[dst[i]], 1.0f);
}

__global__ __launch_bounds__(256) void inv_k(float* __restrict__ cnt, int nN) {
    int i = blockIdx.x * 256 + threadIdx.x;
    if (i < nN) cnt[i] = 1.0f / fmaxf(cnt[i], 1.0f);
}

// ---------------- edge scatter (atomic mean-aggregation numerator) ----------------
// 128 threads per edge (one full feature row), 2 edges per 256-thread block per iter.
__global__ __launch_bounds__(256) void scatter_k(const int* __restrict__ src,
                                                 const int* __restrict__ dst,
                                                 const float* __restrict__ h,
                                                 float* __restrict__ agg, int nE) {
    int lane = threadIdx.x & (HID - 1);
    int sub  = threadIdx.x >> 7;
    for (int e = blockIdx.x * 2 + sub; e < nE; e += gridDim.x * 2) {
        int s = src[e], d = dst[e];
        float v = h[(size_t)s * HID + lane];
        unsafeAtomicAdd(&agg[(size_t)d * HID + lane], v);
    }
}

// ---------------- fused SAGE transform: out = relu((agg*inv)@Wl + h@Wr + bl) ----------------
// 64-row tile in LDS, 256 threads, each thread computes 8 rows x 4 cols.
__global__ __launch_bounds__(256) void sage_gemm_k(
    const float* __restrict__ agg, const float* __restrict__ inv,
    const float* __restrict__ h,
    const float* __restrict__ Wl, const float* __restrict__ bl,
    const float* __restrict__ Wr,
    float* __restrict__ out, int nrows)
{
    __shared__ float sM[64][HID];
    __shared__ float sH[64][HID];
    const int tid  = threadIdx.x;
    const int row0 = blockIdx.x * 64;

    // stage 64 rows x 128 cols of mean (agg*inv) and h
    #pragma unroll
    for (int s = 0; s < 8; ++s) {
        int idx4 = s * 256 + tid;          // 0..2047 float4 slots
        int r = idx4 >> 5;                 // 32 float4 per row
        int c = (idx4 & 31) * 4;
        int gr = row0 + r;
        float4 a, b;
        if (gr < nrows) {
            a = *(const float4*)(agg + (size_t)gr * HID + c);
            float iv = inv[gr];
            a.x *= iv; a.y *= iv; a.z *= iv; a.w *= iv;
            b = *(const float4*)(h + (size_t)gr * HID + c);
        } else {
            a = make_float4(0.f, 0.f, 0.f, 0.f);
            b = a;
        }
        *(float4*)(&sM[r][c]) = a;
        *(float4*)(&sH[r][c]) = b;
    }
    __syncthreads();

    const int tx = tid & 31, ty = tid >> 5;
    const int j0 = tx * 4;                 // 4 output cols
    const int i0 = ty * 8;                 // 8 output rows

    float4 bias = *(const float4*)(bl + j0);
    float acc[8][4];
    #pragma unroll
    for (int r = 0; r < 8; ++r) {
        acc[r][0] = bias.x; acc[r][1] = bias.y; acc[r][2] = bias.z; acc[r][3] = bias.w;
    }

    for (int k = 0; k < HID; k += 4) {
        float4 m[8], hh[8];
        #pragma unroll
        for (int r = 0; r < 8; ++r) {
            m[r]  = *(const float4*)(&sM[i0 + r][k]);   // 2 distinct addrs/wave -> broadcast, free
            hh[r] = *(const float4*)(&sH[i0 + r][k]);
        }
        #pragma unroll
        for (int kk = 0; kk < 4; ++kk) {
            float4 wl = *(const float4*)(Wl + (size_t)(k + kk) * HID + j0);
            float4 wr = *(const float4*)(Wr + (size_t)(k + kk) * HID + j0);
            #pragma unroll
            for (int r = 0; r < 8; ++r) {
                float mv = (&m[r].x)[kk];
                float hv = (&hh[r].x)[kk];
                acc[r][0] += mv * wl.x + hv * wr.x;
                acc[r][1] += mv * wl.y + hv * wr.y;
                acc[r][2] += mv * wl.z + hv * wr.z;
                acc[r][3] += mv * wl.w + hv * wr.w;
            }
        }
    }

    #pragma unroll
    for (int r = 0; r < 8; ++r) {
        int gr = row0 + i0 + r;
        if (gr < nrows) {
            float4 o;
            o.x = fmaxf(acc[r][0], 0.f);
            o.y = fmaxf(acc[r][1], 0.f);
            o.z = fmaxf(acc[r][2], 0.f);
            o.w = fmaxf(acc[r][3], 0.f);
            *(float4*)(out + (size_t)gr * HID + j0) = o;
        }
    }
}

// ---------------- global add pool (atomic; batch is sorted) ----------------
__global__ __launch_bounds__(256) void pool_k(const float* __restrict__ h,
                                              const int* __restrict__ batch,
                                              float* __restrict__ pooled, int nN) {
    int lane = threadIdx.x & (HID - 1);
    int sub  = threadIdx.x >> 7;
    for (int i = blockIdx.x * 2 + sub; i < nN; i += gridDim.x * 2) {
        int g = batch[i];
        unsafeAtomicAdd(&pooled[(size_t)g * HID + lane], h[(size_t)i * HID + lane]);
    }
}

// ---------------- batchnorm stats over graphs -> affine scale/shift ----------------
__global__ __launch_bounds__(HID) void bn_stats_k(const float* __restrict__ pooled,
                                                  const float* __restrict__ gamma,
                                                  const float* __restrict__ beta,
                                                  float* __restrict__ scale,
                                                  float* __restrict__ shift, int nG) {
    int j = threadIdx.x;  // 0..127 feature
    float s = 0.f, s2 = 0.f;
    for (int g = 0; g < nG; ++g) {
        float v = pooled[(size_t)g * HID + j];
        s += v; s2 += v * v;
    }
    float invG = 1.0f / (float)nG;
    float mu = s * invG;
    float var = s2 * invG - mu * mu;
    float rs = rsqrtf(var + 1e-5f) * gamma[j];
    scale[j] = rs;
    shift[j] = beta[j] - mu * rs;
}

// ---------------- final FC: out[g][o] = sum_j normed[g][j] * fcW[j][o] + fcb[o] ----------------
__global__ __launch_bounds__(LATENT) void fc_k(const float* __restrict__ pooled,
                                               const float* __restrict__ scale,
                                               const float* __restrict__ shift,
                                               const float* __restrict__ fcW,
                                               const float* __restrict__ fcb,
                                               float* __restrict__ out, int nG) {
    int g = blockIdx.x;
    int o = threadIdx.x;
    float acc = fcb[o];
    for (int j = 0; j < HID; ++j) {
        float v = pooled[(size_t)g * HID + j] * scale[j] + shift[j];
        acc += v * fcW[(size_t)j * LATENT + o];
    }
    out[(size_t)g * LATENT + o] = acc;
}

extern "C" void kernel_launch(void* const* d_in, const int* in_sizes, int n_in,
                              void* d_out, int out_size, void* d_ws, size_t ws_size,
                              hipStream_t stream) {
    const float* x     = (const float*)d_in[0];
    const int*   ei    = (const int*)d_in[1];
    const int*   batch = (const int*)d_in[2];
    const float* Wl    = (const float*)d_in[3];
    const float* bl    = (const float*)d_in[4];
    const float* Wr    = (const float*)d_in[5];
    const float* gamma = (const float*)d_in[6];
    const float* beta  = (const float*)d_in[7];
    const float* fcW   = (const float*)d_in[8];
    const float* fcb   = (const float*)d_in[9];
    float* out = (float*)d_out;

    const int nN = in_sizes[0] / HID;      // 50000
    const int nE = in_sizes[1] / 2;        // 800000
    const int nG = out_size / LATENT;      // 256
    const int* src = ei;
    const int* dst = ei + nE;

    float* A      = (float*)d_ws;                    // agg scratch
    float* B      = A + (size_t)nN * HID;
    float* C      = B + (size_t)nN * HID;
    float* invc   = C + (size_t)nN * HID;            // degree -> reciprocal, in place
    float* pooled = invc + nN;
    float* scale  = pooled + (size_t)nG * HID;
    float* shift  = scale + HID;

    // degree counts (structure-only: once per call)
    hipMemsetAsync(invc, 0, (size_t)nN * sizeof(float), stream);
    count_edges_k<<<(nE + 255) / 256, 256, 0, stream>>>(dst, invc, nE);
    inv_k<<<(nN + 255) / 256, 256, 0, stream>>>(invc, nN);

    const int SC_BLOCKS = 8192;
    const int gemm_blocks = (nN + 63) / 64;

    const float* hcur = x;
    float* outs[3] = {B, C, B};
    for (int l = 0; l < 3; ++l) {
        hipMemsetAsync(A, 0, (size_t)nN * HID * sizeof(float), stream);
        scatter_k<<<SC_BLOCKS, 256, 0, stream>>>(src, dst, hcur, A, nE);
        sage_gemm_k<<<gemm_blocks, 256, 0, stream>>>(A, invc, hcur,
                                                     Wl + (size_t)l * HID * HID,
                                                     bl + (size_t)l * HID,
                                                     Wr + (size_t)l * HID * HID,
                                                     outs[l], nN);
        hcur = outs[l];
    }

    hipMemsetAsync(pooled, 0, (size_t)nG * HID * sizeof(float), stream);
    pool_k<<<SC_BLOCKS, 256, 0, stream>>>(hcur, batch, pooled, nN);
    bn_stats_k<<<1, HID, 0, stream>>>(pooled, gamma, beta, scale, shift, nG);
    fc_k<<<nG, LATENT, 0, stream>>>(pooled, scale, shift, fcW, fcb, out, nG);
}

// Round 2
// 823.744 us; speedup vs baseline: 1.8243x; 1.8243x over previous
//
#include <hip/hip_runtime.h>
#include <cstdint>
#include <cstddef>

constexpr int HID = 128;
constexpr int LATENT = 64;

// ---------------- CSR build: histogram of dst ----------------
__global__ __launch_bounds__(256) void hist_k(const int* __restrict__ dst,
                                              int* __restrict__ hist, int nE) {
    int i = blockIdx.x * 256 + threadIdx.x;
    if (i < nE) atomicAdd(&hist[dst[i]], 1);
}

// ---------------- one-block exclusive scan over 50k counts ----------------
// also emits offset copy (for permutation) and inv = 1/max(cnt,1)
__global__ __launch_bounds__(1024) void scan_k(const int* __restrict__ hist,
                                               int* __restrict__ row_ptr,
                                               int* __restrict__ offset,
                                               float* __restrict__ inv,
                                               int nN, int nE) {
    __shared__ int part[1024];
    const int t = threadIdx.x;
    const int CH = (nN + 1023) / 1024;
    const int beg = t * CH;
    const int end = min(beg + CH, nN);
    int s = 0;
    for (int i = beg; i < end; ++i) s += hist[i];
    part[t] = s;
    __syncthreads();
    // Hillis-Steele inclusive scan
    for (int d = 1; d < 1024; d <<= 1) {
        int v = (t >= d) ? part[t - d] : 0;
        __syncthreads();
        if (t >= d) part[t] += v;
        __syncthreads();
    }
    int run = (t == 0) ? 0 : part[t - 1];
    for (int i = beg; i < end; ++i) {
        int c = hist[i];
        row_ptr[i] = run;
        offset[i]  = run;
        inv[i] = 1.0f / fmaxf((float)c, 1.0f);
        run += c;
    }
    if (t == 1023) row_ptr[nN] = nE;
}

// ---------------- permutation scatter: bucket src ids by dst ----------------
__global__ __launch_bounds__(256) void perm_k(const int* __restrict__ src,
                                              const int* __restrict__ dst,
                                              int* __restrict__ offset,
                                              int* __restrict__ csr_src, int nE) {
    int i = blockIdx.x * 256 + threadIdx.x;
    if (i < nE) {
        int pos = atomicAdd(&offset[dst[i]], 1);
        csr_src[pos] = src[i];
    }
}

// ---------------- pull-gather mean aggregation: one wave per node ----------------
__global__ __launch_bounds__(256) void gather_k(const int* __restrict__ row_ptr,
                                                const int* __restrict__ csr_src,
                                                const float* __restrict__ inv,
                                                const float* __restrict__ h,
                                                float* __restrict__ mean, int nN) {
    int w = blockIdx.x * 4 + (threadIdx.x >> 6);
    if (w >= nN) return;
    int lane = threadIdx.x & 63;
    int beg = row_ptr[w], end = row_ptr[w + 1];
    const float2* hp = (const float2*)h;   // row stride = 64 float2
    float2 a0 = {0.f, 0.f}, a1 = {0.f, 0.f};
    int i = beg;
    for (; i + 2 <= end; i += 2) {
        int s0 = csr_src[i], s1 = csr_src[i + 1];
        float2 v0 = hp[(size_t)s0 * 64 + lane];
        float2 v1 = hp[(size_t)s1 * 64 + lane];
        a0.x += v0.x; a0.y += v0.y;
        a1.x += v1.x; a1.y += v1.y;
    }
    if (i < end) {
        int s0 = csr_src[i];
        float2 v0 = hp[(size_t)s0 * 64 + lane];
        a0.x += v0.x; a0.y += v0.y;
    }
    float iv = inv[w];
    float2 o = {(a0.x + a1.x) * iv, (a0.y + a1.y) * iv};
    ((float2*)mean)[(size_t)w * 64 + lane] = o;
}

// ---------------- fused SAGE transform: out = relu(mean@Wl + h@Wr + bl) ----------------
// 64-row tile in LDS, 256 threads, each thread computes 8 rows x 4 cols.
__global__ __launch_bounds__(256) void sage_gemm_k(
    const float* __restrict__ mean,
    const float* __restrict__ h,
    const float* __restrict__ Wl, const float* __restrict__ bl,
    const float* __restrict__ Wr,
    float* __restrict__ out, int nrows)
{
    __shared__ float sM[64][HID];
    __shared__ float sH[64][HID];
    const int tid  = threadIdx.x;
    const int row0 = blockIdx.x * 64;

    #pragma unroll
    for (int s = 0; s < 8; ++s) {
        int idx4 = s * 256 + tid;
        int r = idx4 >> 5;
        int c = (idx4 & 31) * 4;
        int gr = row0 + r;
        float4 a, b;
        if (gr < nrows) {
            a = *(const float4*)(mean + (size_t)gr * HID + c);
            b = *(const float4*)(h + (size_t)gr * HID + c);
        } else {
            a = make_float4(0.f, 0.f, 0.f, 0.f);
            b = a;
        }
        *(float4*)(&sM[r][c]) = a;
        *(float4*)(&sH[r][c]) = b;
    }
    __syncthreads();

    const int tx = tid & 31, ty = tid >> 5;
    const int j0 = tx * 4;
    const int i0 = ty * 8;

    float4 bias = *(const float4*)(bl + j0);
    float acc[8][4];
    #pragma unroll
    for (int r = 0; r < 8; ++r) {
        acc[r][0] = bias.x; acc[r][1] = bias.y; acc[r][2] = bias.z; acc[r][3] = bias.w;
    }

    for (int k = 0; k < HID; k += 4) {
        float4 m[8], hh[8];
        #pragma unroll
        for (int r = 0; r < 8; ++r) {
            m[r]  = *(const float4*)(&sM[i0 + r][k]);
            hh[r] = *(const float4*)(&sH[i0 + r][k]);
        }
        #pragma unroll
        for (int kk = 0; kk < 4; ++kk) {
            float4 wl = *(const float4*)(Wl + (size_t)(k + kk) * HID + j0);
            float4 wr = *(const float4*)(Wr + (size_t)(k + kk) * HID + j0);
            #pragma unroll
            for (int r = 0; r < 8; ++r) {
                float mv = (&m[r].x)[kk];
                float hv = (&hh[r].x)[kk];
                acc[r][0] += mv * wl.x + hv * wr.x;
                acc[r][1] += mv * wl.y + hv * wr.y;
                acc[r][2] += mv * wl.z + hv * wr.z;
                acc[r][3] += mv * wl.w + hv * wr.w;
            }
        }
    }

    #pragma unroll
    for (int r = 0; r < 8; ++r) {
        int gr = row0 + i0 + r;
        if (gr < nrows) {
            float4 o;
            o.x = fmaxf(acc[r][0], 0.f);
            o.y = fmaxf(acc[r][1], 0.f);
            o.z = fmaxf(acc[r][2], 0.f);
            o.w = fmaxf(acc[r][3], 0.f);
            *(float4*)(out + (size_t)gr * HID + j0) = o;
        }
    }
}

// ---------------- global add pool (atomic; only 25.6 MB once) ----------------
__global__ __launch_bounds__(256) void pool_k(const float* __restrict__ h,
                                              const int* __restrict__ batch,
                                              float* __restrict__ pooled, int nN) {
    int lane = threadIdx.x & (HID - 1);
    int sub  = threadIdx.x >> 7;
    for (int i = blockIdx.x * 2 + sub; i < nN; i += gridDim.x * 2) {
        int g = batch[i];
        unsafeAtomicAdd(&pooled[(size_t)g * HID + lane], h[(size_t)i * HID + lane]);
    }
}

// ---------------- batchnorm stats over graphs -> affine scale/shift ----------------
__global__ __launch_bounds__(HID) void bn_stats_k(const float* __restrict__ pooled,
                                                  const float* __restrict__ gamma,
                                                  const float* __restrict__ beta,
                                                  float* __restrict__ scale,
                                                  float* __restrict__ shift, int nG) {
    int j = threadIdx.x;
    float s = 0.f, s2 = 0.f;
    for (int g = 0; g < nG; ++g) {
        float v = pooled[(size_t)g * HID + j];
        s += v; s2 += v * v;
    }
    float invG = 1.0f / (float)nG;
    float mu = s * invG;
    float var = s2 * invG - mu * mu;
    float rs = rsqrtf(var + 1e-5f) * gamma[j];
    scale[j] = rs;
    shift[j] = beta[j] - mu * rs;
}

// ---------------- final FC ----------------
__global__ __launch_bounds__(LATENT) void fc_k(const float* __restrict__ pooled,
                                               const float* __restrict__ scale,
                                               const float* __restrict__ shift,
                                               const float* __restrict__ fcW,
                                               const float* __restrict__ fcb,
                                               float* __restrict__ out, int nG) {
    int g = blockIdx.x;
    int o = threadIdx.x;
    float acc = fcb[o];
    for (int j = 0; j < HID; ++j) {
        float v = pooled[(size_t)g * HID + j] * scale[j] + shift[j];
        acc += v * fcW[(size_t)j * LATENT + o];
    }
    out[(size_t)g * LATENT + o] = acc;
}

extern "C" void kernel_launch(void* const* d_in, const int* in_sizes, int n_in,
                              void* d_out, int out_size, void* d_ws, size_t ws_size,
                              hipStream_t stream) {
    const float* x     = (const float*)d_in[0];
    const int*   ei    = (const int*)d_in[1];
    const int*   batch = (const int*)d_in[2];
    const float* Wl    = (const float*)d_in[3];
    const float* bl    = (const float*)d_in[4];
    const float* Wr    = (const float*)d_in[5];
    const float* gamma = (const float*)d_in[6];
    const float* beta  = (const float*)d_in[7];
    const float* fcW   = (const float*)d_in[8];
    const float* fcb   = (const float*)d_in[9];
    float* out = (float*)d_out;

    const int nN = in_sizes[0] / HID;      // 50000
    const int nE = in_sizes[1] / 2;        // 800000
    const int nG = out_size / LATENT;      // 256
    const int* src = ei;
    const int* dst = ei + nE;

    float* mean   = (float*)d_ws;
    float* B      = mean + (size_t)nN * HID;
    float* C      = B + (size_t)nN * HID;
    float* inv    = C + (size_t)nN * HID;
    float* pooled = inv + nN;
    float* scale  = pooled + (size_t)nG * HID;
    float* shift  = scale + HID;
    int*   hist    = (int*)(shift + HID);
    int*   row_ptr = hist + nN;            // nN+1 entries
    int*   offset  = row_ptr + (nN + 1);
    int*   csr_src = offset + nN;

    // ---- CSR build (once per call; ws is re-poisoned each launch) ----
    hipMemsetAsync(hist, 0, (size_t)nN * sizeof(int), stream);
    hist_k<<<(nE + 255) / 256, 256, 0, stream>>>(dst, hist, nE);
    scan_k<<<1, 1024, 0, stream>>>(hist, row_ptr, offset, inv, nN, nE);
    perm_k<<<(nE + 255) / 256, 256, 0, stream>>>(src, dst, offset, csr_src, nE);

    const int gemm_blocks = (nN + 63) / 64;
    const int gather_blocks = (nN + 3) / 4;

    const float* hcur = x;
    float* outs[3] = {B, C, B};
    for (int l = 0; l < 3; ++l) {
        gather_k<<<gather_blocks, 256, 0, stream>>>(row_ptr, csr_src, inv, hcur, mean, nN);
        sage_gemm_k<<<gemm_blocks, 256, 0, stream>>>(mean, hcur,
                                                     Wl + (size_t)l * HID * HID,
                                                     bl + (size_t)l * HID,
                                                     Wr + (size_t)l * HID * HID,
                                                     outs[l], nN);
        hcur = outs[l];
    }

    hipMemsetAsync(pooled, 0, (size_t)nG * HID * sizeof(float), stream);
    pool_k<<<8192, 256, 0, stream>>>(hcur, batch, pooled, nN);
    bn_stats_k<<<1, HID, 0, stream>>>(pooled, gamma, beta, scale, shift, nG);
    fc_k<<<nG, LATENT, 0, stream>>>(pooled, scale, shift, fcW, fcb, out, nG);
}

// Round 3
// 693.448 us; speedup vs baseline: 2.1671x; 1.1879x over previous
//
#include <hip/hip_runtime.h>
#include <cstdint>
#include <cstddef>

constexpr int HID = 128;
constexpr int LATENT = 64;
constexpr int SCAN_B = 1024;   // elems per scan block

// ---------------- CSR build: histogram of dst ----------------
__global__ __launch_bounds__(256) void hist_k(const int* __restrict__ dst,
                                              int* __restrict__ hist, int nE) {
    int i = blockIdx.x * 256 + threadIdx.x;
    if (i < nE) atomicAdd(&hist[dst[i]], 1);
}

// ---------------- 3-phase device-wide exclusive scan ----------------
// Phase A: per-block sums
__global__ __launch_bounds__(SCAN_B) void scan_blocksums_k(const int* __restrict__ hist,
                                                           int* __restrict__ blockSums, int nN) {
    __shared__ int red[SCAN_B / 64];
    int i = blockIdx.x * SCAN_B + threadIdx.x;
    int v = (i < nN) ? hist[i] : 0;
    // wave reduce
    #pragma unroll
    for (int d = 1; d < 64; d <<= 1) v += __shfl_down(v, d, 64);
    int wave = threadIdx.x >> 6, lane = threadIdx.x & 63;
    if (lane == 0) red[wave] = v;
    __syncthreads();
    if (threadIdx.x == 0) {
        int s = 0;
        #pragma unroll
        for (int w = 0; w < SCAN_B / 64; ++w) s += red[w];
        blockSums[blockIdx.x] = s;
    }
}

// Phase B: one wave exclusive-scans the block sums (nB <= 64)
__global__ __launch_bounds__(64) void scan_offsets_k(int* __restrict__ blockSums, int nB) {
    int lane = threadIdx.x;
    int v = (lane < nB) ? blockSums[lane] : 0;
    int incl = v;
    #pragma unroll
    for (int d = 1; d < 64; d <<= 1) {
        int u = __shfl_up(incl, d, 64);
        if (lane >= d) incl += u;
    }
    if (lane < nB) blockSums[lane] = incl - v;   // exclusive offset
}

// Phase C: per-block LDS scan + block offset -> row_ptr/offset/inv
__global__ __launch_bounds__(SCAN_B) void scan_write_k(const int* __restrict__ hist,
                                                       const int* __restrict__ blockSums,
                                                       int* __restrict__ row_ptr,
                                                       int* __restrict__ offset,
                                                       float* __restrict__ inv,
                                                       int nN, int nE) {
    __shared__ int part[SCAN_B];
    int t = threadIdx.x;
    int i = blockIdx.x * SCAN_B + t;
    int c = (i < nN) ? hist[i] : 0;
    part[t] = c;
    __syncthreads();
    // Hillis-Steele inclusive
    #pragma unroll
    for (int d = 1; d < SCAN_B; d <<= 1) {
        int u = (t >= d) ? part[t - d] : 0;
        __syncthreads();
        if (t >= d) part[t] += u;
        __syncthreads();
    }
    if (i < nN) {
        int excl = blockSums[blockIdx.x] + part[t] - c;
        row_ptr[i] = excl;
        offset[i]  = excl;
        inv[i] = 1.0f / fmaxf((float)c, 1.0f);
    }
    if (blockIdx.x == 0 && t == 0) row_ptr[nN] = nE;
}

// ---------------- permutation scatter: bucket src ids by dst ----------------
__global__ __launch_bounds__(256) void perm_k(const int* __restrict__ src,
                                              const int* __restrict__ dst,
                                              int* __restrict__ offset,
                                              int* __restrict__ csr_src, int nE) {
    int i = blockIdx.x * 256 + threadIdx.x;
    if (i < nE) {
        int pos = atomicAdd(&offset[dst[i]], 1);
        csr_src[pos] = src[i];
    }
}

// ---------------- pull-gather mean aggregation: one wave per node ----------------
__global__ __launch_bounds__(256) void gather_k(const int* __restrict__ row_ptr,
                                                const int* __restrict__ csr_src,
                                                const float* __restrict__ inv,
                                                const float* __restrict__ h,
                                                float* __restrict__ mean, int nN) {
    int w = blockIdx.x * 4 + (threadIdx.x >> 6);
    if (w >= nN) return;
    int lane = threadIdx.x & 63;
    int beg = row_ptr[w], end = row_ptr[w + 1];
    const float2* hp = (const float2*)h;   // row stride = 64 float2
    float2 a0 = {0.f, 0.f}, a1 = {0.f, 0.f};
    int i = beg;
    for (; i + 2 <= end; i += 2) {
        int s0 = csr_src[i], s1 = csr_src[i + 1];
        float2 v0 = hp[(size_t)s0 * 64 + lane];
        float2 v1 = hp[(size_t)s1 * 64 + lane];
        a0.x += v0.x; a0.y += v0.y;
        a1.x += v1.x; a1.y += v1.y;
    }
    if (i < end) {
        int s0 = csr_src[i];
        float2 v0 = hp[(size_t)s0 * 64 + lane];
        a0.x += v0.x; a0.y += v0.y;
    }
    float iv = inv[w];
    float2 o = {(a0.x + a1.x) * iv, (a0.y + a1.y) * iv};
    ((float2*)mean)[(size_t)w * 64 + lane] = o;
}

// ---------------- fused SAGE transform: out = relu(mean@Wl + h@Wr + bl) ----------------
__global__ __launch_bounds__(256) void sage_gemm_k(
    const float* __restrict__ mean,
    const float* __restrict__ h,
    const float* __restrict__ Wl, const float* __restrict__ bl,
    const float* __restrict__ Wr,
    float* __restrict__ out, int nrows)
{
    __shared__ float sM[64][HID];
    __shared__ float sH[64][HID];
    const int tid  = threadIdx.x;
    const int row0 = blockIdx.x * 64;

    #pragma unroll
    for (int s = 0; s < 8; ++s) {
        int idx4 = s * 256 + tid;
        int r = idx4 >> 5;
        int c = (idx4 & 31) * 4;
        int gr = row0 + r;
        float4 a, b;
        if (gr < nrows) {
            a = *(const float4*)(mean + (size_t)gr * HID + c);
            b = *(const float4*)(h + (size_t)gr * HID + c);
        } else {
            a = make_float4(0.f, 0.f, 0.f, 0.f);
            b = a;
        }
        *(float4*)(&sM[r][c]) = a;
        *(float4*)(&sH[r][c]) = b;
    }
    __syncthreads();

    const int tx = tid & 31, ty = tid >> 5;
    const int j0 = tx * 4;
    const int i0 = ty * 8;

    float4 bias = *(const float4*)(bl + j0);
    float acc[8][4];
    #pragma unroll
    for (int r = 0; r < 8; ++r) {
        acc[r][0] = bias.x; acc[r][1] = bias.y; acc[r][2] = bias.z; acc[r][3] = bias.w;
    }

    for (int k = 0; k < HID; k += 4) {
        float4 m[8], hh[8];
        #pragma unroll
        for (int r = 0; r < 8; ++r) {
            m[r]  = *(const float4*)(&sM[i0 + r][k]);
            hh[r] = *(const float4*)(&sH[i0 + r][k]);
        }
        #pragma unroll
        for (int kk = 0; kk < 4; ++kk) {
            float4 wl = *(const float4*)(Wl + (size_t)(k + kk) * HID + j0);
            float4 wr = *(const float4*)(Wr + (size_t)(k + kk) * HID + j0);
            #pragma unroll
            for (int r = 0; r < 8; ++r) {
                float mv = (&m[r].x)[kk];
                float hv = (&hh[r].x)[kk];
                acc[r][0] += mv * wl.x + hv * wr.x;
                acc[r][1] += mv * wl.y + hv * wr.y;
                acc[r][2] += mv * wl.z + hv * wr.z;
                acc[r][3] += mv * wl.w + hv * wr.w;
            }
        }
    }

    #pragma unroll
    for (int r = 0; r < 8; ++r) {
        int gr = row0 + i0 + r;
        if (gr < nrows) {
            float4 o;
            o.x = fmaxf(acc[r][0], 0.f);
            o.y = fmaxf(acc[r][1], 0.f);
            o.z = fmaxf(acc[r][2], 0.f);
            o.w = fmaxf(acc[r][3], 0.f);
            *(float4*)(out + (size_t)gr * HID + j0) = o;
        }
    }
}

// ---------------- global add pool (atomic; only 25.6 MB once) ----------------
__global__ __launch_bounds__(256) void pool_k(const float* __restrict__ h,
                                              const int* __restrict__ batch,
                                              float* __restrict__ pooled, int nN) {
    int lane = threadIdx.x & (HID - 1);
    int sub  = threadIdx.x >> 7;
    for (int i = blockIdx.x * 2 + sub; i < nN; i += gridDim.x * 2) {
        int g = batch[i];
        unsafeAtomicAdd(&pooled[(size_t)g * HID + lane], h[(size_t)i * HID + lane]);
    }
}

// ---------------- batchnorm stats over graphs -> affine scale/shift ----------------
__global__ __launch_bounds__(HID) void bn_stats_k(const float* __restrict__ pooled,
                                                  const float* __restrict__ gamma,
                                                  const float* __restrict__ beta,
                                                  float* __restrict__ scale,
                                                  float* __restrict__ shift, int nG) {
    int j = threadIdx.x;
    float s = 0.f, s2 = 0.f;
    for (int g = 0; g < nG; ++g) {
        float v = pooled[(size_t)g * HID + j];
        s += v; s2 += v * v;
    }
    float invG = 1.0f / (float)nG;
    float mu = s * invG;
    float var = s2 * invG - mu * mu;
    float rs = rsqrtf(var + 1e-5f) * gamma[j];
    scale[j] = rs;
    shift[j] = beta[j] - mu * rs;
}

// ---------------- final FC ----------------
__global__ __launch_bounds__(LATENT) void fc_k(const float* __restrict__ pooled,
                                               const float* __restrict__ scale,
                                               const float* __restrict__ shift,
                                               const float* __restrict__ fcW,
                                               const float* __restrict__ fcb,
                                               float* __restrict__ out, int nG) {
    int g = blockIdx.x;
    int o = threadIdx.x;
    float acc = fcb[o];
    for (int j = 0; j < HID; ++j) {
        float v = pooled[(size_t)g * HID + j] * scale[j] + shift[j];
        acc += v * fcW[(size_t)j * LATENT + o];
    }
    out[(size_t)g * LATENT + o] = acc;
}

extern "C" void kernel_launch(void* const* d_in, const int* in_sizes, int n_in,
                              void* d_out, int out_size, void* d_ws, size_t ws_size,
                              hipStream_t stream) {
    const float* x     = (const float*)d_in[0];
    const int*   ei    = (const int*)d_in[1];
    const int*   batch = (const int*)d_in[2];
    const float* Wl    = (const float*)d_in[3];
    const float* bl    = (const float*)d_in[4];
    const float* Wr    = (const float*)d_in[5];
    const float* gamma = (const float*)d_in[6];
    const float* beta  = (const float*)d_in[7];
    const float* fcW   = (const float*)d_in[8];
    const float* fcb   = (const float*)d_in[9];
    float* out = (float*)d_out;

    const int nN = in_sizes[0] / HID;      // 50000
    const int nE = in_sizes[1] / 2;        // 800000
    const int nG = out_size / LATENT;      // 256
    const int* src = ei;
    const int* dst = ei + nE;

    float* mean   = (float*)d_ws;
    float* B      = mean + (size_t)nN * HID;
    float* C      = B + (size_t)nN * HID;
    float* inv    = C + (size_t)nN * HID;
    float* pooled = inv + nN;
    float* scale  = pooled + (size_t)nG * HID;
    float* shift  = scale + HID;
    int*   hist      = (int*)(shift + HID);
    int*   row_ptr   = hist + nN;            // nN+1 entries
    int*   offset    = row_ptr + (nN + 1);
    int*   csr_src   = offset + nN;
    int*   blockSums = csr_src + nE;

    const int nB = (nN + SCAN_B - 1) / SCAN_B;   // 49 <= 64

    // ---- CSR build (once per call; ws is re-poisoned each launch) ----
    hipMemsetAsync(hist, 0, (size_t)nN * sizeof(int), stream);
    hist_k<<<(nE + 255) / 256, 256, 0, stream>>>(dst, hist, nE);
    scan_blocksums_k<<<nB, SCAN_B, 0, stream>>>(hist, blockSums, nN);
    scan_offsets_k<<<1, 64, 0, stream>>>(blockSums, nB);
    scan_write_k<<<nB, SCAN_B, 0, stream>>>(hist, blockSums, row_ptr, offset, inv, nN, nE);
    perm_k<<<(nE + 255) / 256, 256, 0, stream>>>(src, dst, offset, csr_src, nE);

    const int gemm_blocks = (nN + 63) / 64;
    const int gather_blocks = (nN + 3) / 4;

    const float* hcur = x;
    float* outs[3] = {B, C, B};
    for (int l = 0; l < 3; ++l) {
        gather_k<<<gather_blocks, 256, 0, stream>>>(row_ptr, csr_src, inv, hcur, mean, nN);
        sage_gemm_k<<<gemm_blocks, 256, 0, stream>>>(mean, hcur,
                                                     Wl + (size_t)l * HID * HID,
                                                     bl + (size_t)l * HID,
                                                     Wr + (size_t)l * HID * HID,
                                                     outs[l], nN);
        hcur = outs[l];
    }

    hipMemsetAsync(pooled, 0, (size_t)nG * HID * sizeof(float), stream);
    pool_k<<<8192, 256, 0, stream>>>(hcur, batch, pooled, nN);
    bn_stats_k<<<1, HID, 0, stream>>>(pooled, gamma, beta, scale, shift, nG);
    fc_k<<<nG, LATENT, 0, stream>>>(pooled, scale, shift, fcW, fcb, out, nG);
}

// Round 4
// 547.512 us; speedup vs baseline: 2.7447x; 1.2665x over previous
//
#include <hip/hip_runtime.h>
#include <cstdint>
#include <cstddef>

constexpr int HID = 128;
constexpr int LATENT = 64;
constexpr int SCAN_B = 1024;

typedef __attribute__((ext_vector_type(8))) short short8;
typedef __attribute__((ext_vector_type(4))) float f32x4;

__device__ inline unsigned short f2bf(float f) {
    unsigned u = __float_as_uint(f);
    u += 0x7fff + ((u >> 16) & 1);          // RNE
    return (unsigned short)(u >> 16);
}
__device__ inline unsigned pack_bf16x2(float lo, float hi) {
    unsigned ulo = __float_as_uint(lo);
    unsigned uhi = __float_as_uint(hi);
    ulo += 0x7fff + ((ulo >> 16) & 1);
    uhi += 0x7fff + ((uhi >> 16) & 1);
    return (ulo >> 16) | (uhi & 0xffff0000u);
}

// ---------------- CSR build: histogram of dst ----------------
__global__ __launch_bounds__(256) void hist_k(const int* __restrict__ dst,
                                              int* __restrict__ hist, int nE) {
    int i = blockIdx.x * 256 + threadIdx.x;
    if (i < nE) atomicAdd(&hist[dst[i]], 1);
}

// ---------------- 3-phase device-wide exclusive scan ----------------
__global__ __launch_bounds__(SCAN_B) void scan_blocksums_k(const int* __restrict__ hist,
                                                           int* __restrict__ blockSums, int nN) {
    __shared__ int red[SCAN_B / 64];
    int i = blockIdx.x * SCAN_B + threadIdx.x;
    int v = (i < nN) ? hist[i] : 0;
    #pragma unroll
    for (int d = 1; d < 64; d <<= 1) v += __shfl_down(v, d, 64);
    int wave = threadIdx.x >> 6, lane = threadIdx.x & 63;
    if (lane == 0) red[wave] = v;
    __syncthreads();
    if (threadIdx.x == 0) {
        int s = 0;
        #pragma unroll
        for (int w = 0; w < SCAN_B / 64; ++w) s += red[w];
        blockSums[blockIdx.x] = s;
    }
}

__global__ __launch_bounds__(64) void scan_offsets_k(int* __restrict__ blockSums, int nB) {
    int lane = threadIdx.x;
    int v = (lane < nB) ? blockSums[lane] : 0;
    int incl = v;
    #pragma unroll
    for (int d = 1; d < 64; d <<= 1) {
        int u = __shfl_up(incl, d, 64);
        if (lane >= d) incl += u;
    }
    if (lane < nB) blockSums[lane] = incl - v;
}

__global__ __launch_bounds__(SCAN_B) void scan_write_k(const int* __restrict__ hist,
                                                       const int* __restrict__ blockSums,
                                                       int* __restrict__ row_ptr,
                                                       int* __restrict__ offset,
                                                       float* __restrict__ inv,
                                                       int nN, int nE) {
    __shared__ int part[SCAN_B];
    int t = threadIdx.x;
    int i = blockIdx.x * SCAN_B + t;
    int c = (i < nN) ? hist[i] : 0;
    part[t] = c;
    __syncthreads();
    #pragma unroll
    for (int d = 1; d < SCAN_B; d <<= 1) {
        int u = (t >= d) ? part[t - d] : 0;
        __syncthreads();
        if (t >= d) part[t] += u;
        __syncthreads();
    }
    if (i < nN) {
        int excl = blockSums[blockIdx.x] + part[t] - c;
        row_ptr[i] = excl;
        offset[i]  = excl;
        inv[i] = 1.0f / fmaxf((float)c, 1.0f);
    }
    if (blockIdx.x == 0 && t == 0) row_ptr[nN] = nE;
}

// ---------------- permutation scatter: bucket src ids by dst ----------------
__global__ __launch_bounds__(256) void perm_k(const int* __restrict__ src,
                                              const int* __restrict__ dst,
                                              int* __restrict__ offset,
                                              int* __restrict__ csr_src, int nE) {
    int i = blockIdx.x * 256 + threadIdx.x;
    if (i < nE) {
        int pos = atomicAdd(&offset[dst[i]], 1);
        csr_src[pos] = src[i];
    }
}

// ---------------- f32 -> bf16 conversion (x input, once) ----------------
__global__ __launch_bounds__(256) void tobf16_k(const float* __restrict__ in,
                                                unsigned* __restrict__ out, int n2) {
    int i = blockIdx.x * 256 + threadIdx.x;
    if (i < n2) {
        float2 v = ((const float2*)in)[i];
        out[i] = pack_bf16x2(v.x, v.y);
    }
}

// ---------------- weight conversion: WT[l][n][k] bf16, k in [0,256) ----------------
// k<128 -> Wl[l][k][n]; k>=128 -> Wr[l][k-128][n]   (transposed for B-frag reads)
__global__ __launch_bounds__(256) void convW_k(const float* __restrict__ Wl,
                                               const float* __restrict__ Wr,
                                               unsigned short* __restrict__ WT) {
    int idx = blockIdx.x * 256 + threadIdx.x;
    if (idx >= 3 * 128 * 256) return;
    int l = idx / (128 * 256);
    int rem = idx % (128 * 256);
    int n = rem / 256;
    int k = rem % 256;
    float v = (k < 128) ? Wl[(size_t)l * 128 * 128 + (size_t)k * 128 + n]
                        : Wr[(size_t)l * 128 * 128 + (size_t)(k - 128) * 128 + n];
    WT[idx] = f2bf(v);
}

// ---------------- pull-gather mean aggregation (bf16 rows, f32 accum) ----------------
__global__ __launch_bounds__(256) void gather_k(const int* __restrict__ row_ptr,
                                                const int* __restrict__ csr_src,
                                                const float* __restrict__ inv,
                                                const unsigned* __restrict__ h2,
                                                unsigned* __restrict__ mean2, int nN) {
    int w = blockIdx.x * 4 + (threadIdx.x >> 6);
    if (w >= nN) return;
    int lane = threadIdx.x & 63;
    int beg = row_ptr[w], end = row_ptr[w + 1];
    float a0 = 0.f, a1 = 0.f, b0 = 0.f, b1 = 0.f;
    int i = beg;
    for (; i + 2 <= end; i += 2) {
        int s0 = csr_src[i], s1 = csr_src[i + 1];
        unsigned u0 = h2[(size_t)s0 * 64 + lane];
        unsigned u1 = h2[(size_t)s1 * 64 + lane];
        a0 += __uint_as_float(u0 << 16);
        a1 += __uint_as_float(u0 & 0xffff0000u);
        b0 += __uint_as_float(u1 << 16);
        b1 += __uint_as_float(u1 & 0xffff0000u);
    }
    if (i < end) {
        unsigned u0 = h2[(size_t)csr_src[i] * 64 + lane];
        a0 += __uint_as_float(u0 << 16);
        a1 += __uint_as_float(u0 & 0xffff0000u);
    }
    float iv = inv[w];
    mean2[(size_t)w * 64 + lane] = pack_bf16x2((a0 + b0) * iv, (a1 + b1) * iv);
}

// ---------------- MFMA SAGE transform: out = relu([mean|h] @ WT^T + bl), bf16 ----------------
// Block: 256 thr = 4 waves, each wave 16 rows x 128 cols. B (256x128 weights,
// n-major) staged in 64KB LDS with XOR swizzle on 16B units to kill bank conflicts.
__global__ __launch_bounds__(256) void sage_mfma_k(
    const unsigned short* __restrict__ mean,
    const unsigned short* __restrict__ h,
    const unsigned short* __restrict__ WT,   // [128][256] bf16
    const float* __restrict__ bl,
    unsigned short* __restrict__ out, int nN)
{
    __shared__ unsigned short sB[128 * 256];   // exactly 64 KB

    // fill: unit = 16B (8 bf16); row n stride 256 elems; unit' = unit ^ ((n&7)<<2)
    {
        int row = threadIdx.x >> 1, half = threadIdx.x & 1;
        const short8* src = (const short8*)(WT + row * 256 + half * 128);
        int sw = (row & 7) << 2;
        #pragma unroll
        for (int j = 0; j < 16; ++j) {
            int unit = half * 16 + j;
            int unit2 = unit ^ sw;
            *(short8*)(sB + row * 256 + unit2 * 8) = src[j];
        }
    }
    __syncthreads();

    const int wave = threadIdx.x >> 6;
    const int lane = threadIdx.x & 63;
    const int m = lane & 15;        // A row within tile / B col within tile / C col
    const int q = lane >> 4;        // quad
    const int row = blockIdx.x * 64 + wave * 16 + m;
    const int rowc = min(row, nN - 1);
    const int swm = (m & 7) << 2;

    f32x4 acc[8] = {};
    #pragma unroll
    for (int ks = 0; ks < 8; ++ks) {
        const unsigned short* Aptr = (ks < 4) ? mean : h;
        short8 a = *(const short8*)(Aptr + (size_t)rowc * HID + (ks & 3) * 32 + q * 8);
        #pragma unroll
        for (int t = 0; t < 8; ++t) {
            int unit2 = (ks * 4 + q) ^ swm;
            short8 b = *(const short8*)(sB + (t * 16 + m) * 256 + unit2 * 8);
            acc[t] = __builtin_amdgcn_mfma_f32_16x16x32_bf16(a, b, acc[t], 0, 0, 0);
        }
    }

    // C/D: col = lane&15 (=m), row = q*4 + reg
    int orow_base = blockIdx.x * 64 + wave * 16 + q * 4;
    #pragma unroll
    for (int t = 0; t < 8; ++t) {
        float bias = bl[t * 16 + m];
        #pragma unroll
        for (int r = 0; r < 4; ++r) {
            int orow = orow_base + r;
            if (orow < nN) {
                float v = fmaxf(acc[t][r] + bias, 0.f);
                out[(size_t)orow * HID + t * 16 + m] = f2bf(v);
            }
        }
    }
}

// ---------------- global add pool (bf16 in, f32 atomic out) ----------------
__global__ __launch_bounds__(256) void pool_k(const unsigned* __restrict__ h2,
                                              const int* __restrict__ batch,
                                              float* __restrict__ pooled, int nN) {
    int lane = threadIdx.x & 63;
    int sub  = threadIdx.x >> 6;
    for (int i = blockIdx.x * 4 + sub; i < nN; i += gridDim.x * 4) {
        int g = batch[i];
        unsigned u = h2[(size_t)i * 64 + lane];
        unsafeAtomicAdd(&pooled[(size_t)g * HID + 2 * lane],     __uint_as_float(u << 16));
        unsafeAtomicAdd(&pooled[(size_t)g * HID + 2 * lane + 1], __uint_as_float(u & 0xffff0000u));
    }
}

// ---------------- batchnorm stats over graphs -> affine scale/shift ----------------
__global__ __launch_bounds__(HID) void bn_stats_k(const float* __restrict__ pooled,
                                                  const float* __restrict__ gamma,
                                                  const float* __restrict__ beta,
                                                  float* __restrict__ scale,
                                                  float* __restrict__ shift, int nG) {
    int j = threadIdx.x;
    float s = 0.f, s2 = 0.f;
    for (int g = 0; g < nG; ++g) {
        float v = pooled[(size_t)g * HID + j];
        s += v; s2 += v * v;
    }
    float invG = 1.0f / (float)nG;
    float mu = s * invG;
    float var = s2 * invG - mu * mu;
    float rs = rsqrtf(var + 1e-5f) * gamma[j];
    scale[j] = rs;
    shift[j] = beta[j] - mu * rs;
}

// ---------------- final FC ----------------
__global__ __launch_bounds__(LATENT) void fc_k(const float* __restrict__ pooled,
                                               const float* __restrict__ scale,
                                               const float* __restrict__ shift,
                                               const float* __restrict__ fcW,
                                               const float* __restrict__ fcb,
                                               float* __restrict__ out, int nG) {
    int g = blockIdx.x;
    int o = threadIdx.x;
    float acc = fcb[o];
    for (int j = 0; j < HID; ++j) {
        float v = pooled[(size_t)g * HID + j] * scale[j] + shift[j];
        acc += v * fcW[(size_t)j * LATENT + o];
    }
    out[(size_t)g * LATENT + o] = acc;
}

extern "C" void kernel_launch(void* const* d_in, const int* in_sizes, int n_in,
                              void* d_out, int out_size, void* d_ws, size_t ws_size,
                              hipStream_t stream) {
    const float* x     = (const float*)d_in[0];
    const int*   ei    = (const int*)d_in[1];
    const int*   batch = (const int*)d_in[2];
    const float* Wl    = (const float*)d_in[3];
    const float* bl    = (const float*)d_in[4];
    const float* Wr    = (const float*)d_in[5];
    const float* gamma = (const float*)d_in[6];
    const float* beta  = (const float*)d_in[7];
    const float* fcW   = (const float*)d_in[8];
    const float* fcb   = (const float*)d_in[9];
    float* out = (float*)d_out;

    const int nN = in_sizes[0] / HID;      // 50000
    const int nE = in_sizes[1] / 2;        // 800000
    const int nG = out_size / LATENT;      // 256
    const int* src = ei;
    const int* dst = ei + nE;

    unsigned short* hx   = (unsigned short*)d_ws;           // nN*HID bf16
    unsigned short* B1   = hx + (size_t)nN * HID;
    unsigned short* B2   = B1 + (size_t)nN * HID;
    unsigned short* mean = B2 + (size_t)nN * HID;
    unsigned short* WT   = mean + (size_t)nN * HID;         // 3*128*256 bf16
    float* inv    = (float*)(WT + 3 * 128 * 256);
    float* pooled = inv + nN;
    float* scale  = pooled + (size_t)nG * HID;
    float* shift  = scale + HID;
    int*   hist      = (int*)(shift + HID);
    int*   row_ptr   = hist + nN;
    int*   offset    = row_ptr + (nN + 1);
    int*   csr_src   = offset + nN;
    int*   blockSums = csr_src + nE;

    const int nB = (nN + SCAN_B - 1) / SCAN_B;

    // ---- CSR build ----
    hipMemsetAsync(hist, 0, (size_t)nN * sizeof(int), stream);
    hist_k<<<(nE + 255) / 256, 256, 0, stream>>>(dst, hist, nE);
    scan_blocksums_k<<<nB, SCAN_B, 0, stream>>>(hist, blockSums, nN);
    scan_offsets_k<<<1, 64, 0, stream>>>(blockSums, nB);
    scan_write_k<<<nB, SCAN_B, 0, stream>>>(hist, blockSums, row_ptr, offset, inv, nN, nE);
    perm_k<<<(nE + 255) / 256, 256, 0, stream>>>(src, dst, offset, csr_src, nE);

    // ---- precompute bf16 buffers ----
    tobf16_k<<<((nN * HID / 2) + 255) / 256, 256, 0, stream>>>(x, (unsigned*)hx, nN * HID / 2);
    convW_k<<<(3 * 128 * 256 + 255) / 256, 256, 0, stream>>>(Wl, Wr, WT);

    const int gather_blocks = (nN + 3) / 4;
    const int gemm_blocks = (nN + 63) / 64;

    const unsigned short* hcur = hx;
    unsigned short* outs[3] = {B1, B2, B1};
    for (int l = 0; l < 3; ++l) {
        gather_k<<<gather_blocks, 256, 0, stream>>>(row_ptr, csr_src, inv,
                                                    (const unsigned*)hcur, (unsigned*)mean, nN);
        sage_mfma_k<<<gemm_blocks, 256, 0, stream>>>(mean, hcur,
                                                     WT + (size_t)l * 128 * 256,
                                                     bl + (size_t)l * HID,
                                                     outs[l], nN);
        hcur = outs[l];
    }

    hipMemsetAsync(pooled, 0, (size_t)nG * HID * sizeof(float), stream);
    pool_k<<<4096, 256, 0, stream>>>((const unsigned*)hcur, batch, pooled, nN);
    bn_stats_k<<<1, HID, 0, stream>>>(pooled, gamma, beta, scale, shift, nG);
    fc_k<<<nG, LATENT, 0, stream>>>(pooled, scale, shift, fcW, fcb, out, nG);
}

// Round 5
// 438.899 us; speedup vs baseline: 3.4239x; 1.2475x over previous
//
#include <hip/hip_runtime.h>
#include <cstdint>
#include <cstddef>

constexpr int HID = 128;
constexpr int LATENT = 64;
constexpr int SCAN_B = 1024;

typedef __attribute__((ext_vector_type(8))) short short8;
typedef __attribute__((ext_vector_type(4))) float f32x4;

__device__ inline unsigned short f2bf(float f) {
    unsigned u = __float_as_uint(f);
    u += 0x7fff + ((u >> 16) & 1);          // RNE
    return (unsigned short)(u >> 16);
}
__device__ inline unsigned pack_bf16x2(float lo, float hi) {
    unsigned ulo = __float_as_uint(lo);
    unsigned uhi = __float_as_uint(hi);
    ulo += 0x7fff + ((ulo >> 16) & 1);
    uhi += 0x7fff + ((uhi >> 16) & 1);
    return (ulo >> 16) | (uhi & 0xffff0000u);
}

// ---------------- CSR build: histogram of dst ----------------
__global__ __launch_bounds__(256) void hist_k(const int* __restrict__ dst,
                                              int* __restrict__ hist, int nE) {
    int i = blockIdx.x * 256 + threadIdx.x;
    if (i < nE) atomicAdd(&hist[dst[i]], 1);
}

// ---------------- 3-phase device-wide exclusive scan ----------------
__global__ __launch_bounds__(SCAN_B) void scan_blocksums_k(const int* __restrict__ hist,
                                                           int* __restrict__ blockSums, int nN) {
    __shared__ int red[SCAN_B / 64];
    int i = blockIdx.x * SCAN_B + threadIdx.x;
    int v = (i < nN) ? hist[i] : 0;
    #pragma unroll
    for (int d = 1; d < 64; d <<= 1) v += __shfl_down(v, d, 64);
    int wave = threadIdx.x >> 6, lane = threadIdx.x & 63;
    if (lane == 0) red[wave] = v;
    __syncthreads();
    if (threadIdx.x == 0) {
        int s = 0;
        #pragma unroll
        for (int w = 0; w < SCAN_B / 64; ++w) s += red[w];
        blockSums[blockIdx.x] = s;
    }
}

__global__ __launch_bounds__(64) void scan_offsets_k(int* __restrict__ blockSums, int nB) {
    int lane = threadIdx.x;
    int v = (lane < nB) ? blockSums[lane] : 0;
    int incl = v;
    #pragma unroll
    for (int d = 1; d < 64; d <<= 1) {
        int u = __shfl_up(incl, d, 64);
        if (lane >= d) incl += u;
    }
    if (lane < nB) blockSums[lane] = incl - v;
}

__global__ __launch_bounds__(SCAN_B) void scan_write_k(const int* __restrict__ hist,
                                                       const int* __restrict__ blockSums,
                                                       int* __restrict__ row_ptr,
                                                       int* __restrict__ offset,
                                                       float* __restrict__ inv,
                                                       int nN, int nE) {
    __shared__ int part[SCAN_B];
    int t = threadIdx.x;
    int i = blockIdx.x * SCAN_B + t;
    int c = (i < nN) ? hist[i] : 0;
    part[t] = c;
    __syncthreads();
    #pragma unroll
    for (int d = 1; d < SCAN_B; d <<= 1) {
        int u = (t >= d) ? part[t - d] : 0;
        __syncthreads();
        if (t >= d) part[t] += u;
        __syncthreads();
    }
    if (i < nN) {
        int excl = blockSums[blockIdx.x] + part[t] - c;
        row_ptr[i] = excl;
        offset[i]  = excl;
        inv[i] = 1.0f / fmaxf((float)c, 1.0f);
    }
    if (blockIdx.x == 0 && t == 0) row_ptr[nN] = nE;
}

// ---------------- permutation scatter: bucket src ids by dst ----------------
__global__ __launch_bounds__(256) void perm_k(const int* __restrict__ src,
                                              const int* __restrict__ dst,
                                              int* __restrict__ offset,
                                              int* __restrict__ csr_src, int nE) {
    int i = blockIdx.x * 256 + threadIdx.x;
    if (i < nE) {
        int pos = atomicAdd(&offset[dst[i]], 1);
        csr_src[pos] = src[i];
    }
}

// ---------------- f32 -> bf16 conversion (x input, once) ----------------
__global__ __launch_bounds__(256) void tobf16_k(const float* __restrict__ in,
                                                unsigned* __restrict__ out, int n2) {
    int i = blockIdx.x * 256 + threadIdx.x;
    if (i < n2) {
        float2 v = ((const float2*)in)[i];
        out[i] = pack_bf16x2(v.x, v.y);
    }
}

// ---------------- weight conversion: WT[l][n][k] bf16, k in [0,256) ----------------
__global__ __launch_bounds__(256) void convW_k(const float* __restrict__ Wl,
                                               const float* __restrict__ Wr,
                                               unsigned short* __restrict__ WT) {
    int idx = blockIdx.x * 256 + threadIdx.x;
    if (idx >= 3 * 128 * 256) return;
    int l = idx / (128 * 256);
    int rem = idx % (128 * 256);
    int n = rem / 256;
    int k = rem % 256;
    float v = (k < 128) ? Wl[(size_t)l * 128 * 128 + (size_t)k * 128 + n]
                        : Wr[(size_t)l * 128 * 128 + (size_t)(k - 128) * 128 + n];
    WT[idx] = f2bf(v);
}

// ---------------- pull-gather mean aggregation, index-broadcast + 4x ILP ----------------
__global__ __launch_bounds__(256) void gather_k(const int* __restrict__ row_ptr,
                                                const int* __restrict__ csr_src,
                                                const float* __restrict__ inv,
                                                const unsigned* __restrict__ h2,
                                                unsigned* __restrict__ mean2, int nN) {
    int w = blockIdx.x * 4 + (threadIdx.x >> 6);
    if (w >= nN) return;
    int lane = threadIdx.x & 63;
    int beg = row_ptr[w], end = row_ptr[w + 1];
    float a0 = 0.f, a1 = 0.f, b0 = 0.f, b1 = 0.f;
    float c0 = 0.f, c1 = 0.f, d0 = 0.f, d1 = 0.f;
    for (int base = beg; base < end; base += 64) {
        int n = min(64, end - base);
        // one coalesced load of up to 64 indices; broadcast via shfl (no dep chain)
        int idx = (lane < n) ? csr_src[base + lane] : 0;
        int j = 0;
        for (; j + 4 <= n; j += 4) {
            int s0 = __shfl(idx, j, 64);
            int s1 = __shfl(idx, j + 1, 64);
            int s2 = __shfl(idx, j + 2, 64);
            int s3 = __shfl(idx, j + 3, 64);
            unsigned u0 = h2[(size_t)s0 * 64 + lane];
            unsigned u1 = h2[(size_t)s1 * 64 + lane];
            unsigned u2 = h2[(size_t)s2 * 64 + lane];
            unsigned u3 = h2[(size_t)s3 * 64 + lane];
            a0 += __uint_as_float(u0 << 16); a1 += __uint_as_float(u0 & 0xffff0000u);
            b0 += __uint_as_float(u1 << 16); b1 += __uint_as_float(u1 & 0xffff0000u);
            c0 += __uint_as_float(u2 << 16); c1 += __uint_as_float(u2 & 0xffff0000u);
            d0 += __uint_as_float(u3 << 16); d1 += __uint_as_float(u3 & 0xffff0000u);
        }
        for (; j < n; ++j) {
            int s0 = __shfl(idx, j, 64);
            unsigned u0 = h2[(size_t)s0 * 64 + lane];
            a0 += __uint_as_float(u0 << 16); a1 += __uint_as_float(u0 & 0xffff0000u);
        }
    }
    float iv = inv[w];
    mean2[(size_t)w * 64 + lane] = pack_bf16x2((a0 + b0 + c0 + d0) * iv,
                                               (a1 + b1 + c1 + d1) * iv);
}

// ---------------- MFMA SAGE transform: out = relu([mean|h] @ WT^T + bl), bf16 ----------------
__global__ __launch_bounds__(256) void sage_mfma_k(
    const unsigned short* __restrict__ mean,
    const unsigned short* __restrict__ h,
    const unsigned short* __restrict__ WT,   // [128][256] bf16
    const float* __restrict__ bl,
    unsigned short* __restrict__ out, int nN)
{
    __shared__ unsigned short sB[128 * 256];   // exactly 64 KB

    {
        int row = threadIdx.x >> 1, half = threadIdx.x & 1;
        const short8* src = (const short8*)(WT + row * 256 + half * 128);
        int sw = (row & 7) << 2;
        #pragma unroll
        for (int j = 0; j < 16; ++j) {
            int unit = half * 16 + j;
            int unit2 = unit ^ sw;
            *(short8*)(sB + row * 256 + unit2 * 8) = src[j];
        }
    }
    __syncthreads();

    const int wave = threadIdx.x >> 6;
    const int lane = threadIdx.x & 63;
    const int m = lane & 15;
    const int q = lane >> 4;
    const int row = blockIdx.x * 64 + wave * 16 + m;
    const int rowc = min(row, nN - 1);
    const int swm = (m & 7) << 2;

    f32x4 acc[8] = {};
    #pragma unroll
    for (int ks = 0; ks < 8; ++ks) {
        const unsigned short* Aptr = (ks < 4) ? mean : h;
        short8 a = *(const short8*)(Aptr + (size_t)rowc * HID + (ks & 3) * 32 + q * 8);
        #pragma unroll
        for (int t = 0; t < 8; ++t) {
            int unit2 = (ks * 4 + q) ^ swm;
            short8 b = *(const short8*)(sB + (t * 16 + m) * 256 + unit2 * 8);
            acc[t] = __builtin_amdgcn_mfma_f32_16x16x32_bf16(a, b, acc[t], 0, 0, 0);
        }
    }

    int orow_base = blockIdx.x * 64 + wave * 16 + q * 4;
    #pragma unroll
    for (int t = 0; t < 8; ++t) {
        float bias = bl[t * 16 + m];
        #pragma unroll
        for (int r = 0; r < 4; ++r) {
            int orow = orow_base + r;
            if (orow < nN) {
                float v = fmaxf(acc[t][r] + bias, 0.f);
                out[(size_t)orow * HID + t * 16 + m] = f2bf(v);
            }
        }
    }
}

// ---------------- segmented pool (batch sorted): one block per graph ----------------
__global__ __launch_bounds__(256) void pool_seg_k(const unsigned* __restrict__ h2,
                                                  const int* __restrict__ batch,
                                                  float* __restrict__ pooled, int nN) {
    int g = blockIdx.x;
    // lower_bound(g) and lower_bound(g+1)
    int lo = 0, hi = nN;
    while (lo < hi) { int mid = (lo + hi) >> 1; if (batch[mid] < g) lo = mid + 1; else hi = mid; }
    int beg = lo;
    hi = nN;
    while (lo < hi) { int mid = (lo + hi) >> 1; if (batch[mid] <= g) lo = mid + 1; else hi = mid; }
    int end = lo;

    int lane = threadIdx.x & 63;
    int sub  = threadIdx.x >> 6;          // 4 waves
    float s0 = 0.f, s1 = 0.f;
    for (int i = beg + sub; i < end; i += 4) {
        unsigned u = h2[(size_t)i * 64 + lane];
        s0 += __uint_as_float(u << 16);
        s1 += __uint_as_float(u & 0xffff0000u);
    }
    __shared__ float red[4][HID];
    red[sub][2 * lane]     = s0;
    red[sub][2 * lane + 1] = s1;
    __syncthreads();
    if (sub == 0) {
        float v0 = red[0][2 * lane] + red[1][2 * lane] + red[2][2 * lane] + red[3][2 * lane];
        float v1 = red[0][2 * lane + 1] + red[1][2 * lane + 1] + red[2][2 * lane + 1] + red[3][2 * lane + 1];
        pooled[(size_t)g * HID + 2 * lane]     = v0;
        pooled[(size_t)g * HID + 2 * lane + 1] = v1;
    }
}

// ---------------- batchnorm stats over graphs -> affine scale/shift ----------------
__global__ __launch_bounds__(HID) void bn_stats_k(const float* __restrict__ pooled,
                                                  const float* __restrict__ gamma,
                                                  const float* __restrict__ beta,
                                                  float* __restrict__ scale,
                                                  float* __restrict__ shift, int nG) {
    int j = threadIdx.x;
    float s = 0.f, s2 = 0.f;
    for (int g = 0; g < nG; ++g) {
        float v = pooled[(size_t)g * HID + j];
        s += v; s2 += v * v;
    }
    float invG = 1.0f / (float)nG;
    float mu = s * invG;
    float var = s2 * invG - mu * mu;
    float rs = rsqrtf(var + 1e-5f) * gamma[j];
    scale[j] = rs;
    shift[j] = beta[j] - mu * rs;
}

// ---------------- final FC ----------------
__global__ __launch_bounds__(LATENT) void fc_k(const float* __restrict__ pooled,
                                               const float* __restrict__ scale,
                                               const float* __restrict__ shift,
                                               const float* __restrict__ fcW,
                                               const float* __restrict__ fcb,
                                               float* __restrict__ out, int nG) {
    int g = blockIdx.x;
    int o = threadIdx.x;
    float acc = fcb[o];
    for (int j = 0; j < HID; ++j) {
        float v = pooled[(size_t)g * HID + j] * scale[j] + shift[j];
        acc += v * fcW[(size_t)j * LATENT + o];
    }
    out[(size_t)g * LATENT + o] = acc;
}

extern "C" void kernel_launch(void* const* d_in, const int* in_sizes, int n_in,
                              void* d_out, int out_size, void* d_ws, size_t ws_size,
                              hipStream_t stream) {
    const float* x     = (const float*)d_in[0];
    const int*   ei    = (const int*)d_in[1];
    const int*   batch = (const int*)d_in[2];
    const float* Wl    = (const float*)d_in[3];
    const float* bl    = (const float*)d_in[4];
    const float* Wr    = (const float*)d_in[5];
    const float* gamma = (const float*)d_in[6];
    const float* beta  = (const float*)d_in[7];
    const float* fcW   = (const float*)d_in[8];
    const float* fcb   = (const float*)d_in[9];
    float* out = (float*)d_out;

    const int nN = in_sizes[0] / HID;      // 50000
    const int nE = in_sizes[1] / 2;        // 800000
    const int nG = out_size / LATENT;      // 256
    const int* src = ei;
    const int* dst = ei + nE;

    unsigned short* hx   = (unsigned short*)d_ws;           // nN*HID bf16
    unsigned short* B1   = hx + (size_t)nN * HID;
    unsigned short* B2   = B1 + (size_t)nN * HID;
    unsigned short* mean = B2 + (size_t)nN * HID;
    unsigned short* WT   = mean + (size_t)nN * HID;         // 3*128*256 bf16
    float* inv    = (float*)(WT + 3 * 128 * 256);
    float* pooled = inv + nN;
    float* scale  = pooled + (size_t)nG * HID;
    float* shift  = scale + HID;
    int*   hist      = (int*)(shift + HID);
    int*   row_ptr   = hist + nN;
    int*   offset    = row_ptr + (nN + 1);
    int*   csr_src   = offset + nN;
    int*   blockSums = csr_src + nE;

    const int nB = (nN + SCAN_B - 1) / SCAN_B;

    // ---- CSR build ----
    hipMemsetAsync(hist, 0, (size_t)nN * sizeof(int), stream);
    hist_k<<<(nE + 255) / 256, 256, 0, stream>>>(dst, hist, nE);
    scan_blocksums_k<<<nB, SCAN_B, 0, stream>>>(hist, blockSums, nN);
    scan_offsets_k<<<1, 64, 0, stream>>>(blockSums, nB);
    scan_write_k<<<nB, SCAN_B, 0, stream>>>(hist, blockSums, row_ptr, offset, inv, nN, nE);
    perm_k<<<(nE + 255) / 256, 256, 0, stream>>>(src, dst, offset, csr_src, nE);

    // ---- precompute bf16 buffers ----
    tobf16_k<<<((nN * HID / 2) + 255) / 256, 256, 0, stream>>>(x, (unsigned*)hx, nN * HID / 2);
    convW_k<<<(3 * 128 * 256 + 255) / 256, 256, 0, stream>>>(Wl, Wr, WT);

    const int gather_blocks = (nN + 3) / 4;
    const int gemm_blocks = (nN + 63) / 64;

    const unsigned short* hcur = hx;
    unsigned short* outs[3] = {B1, B2, B1};
    for (int l = 0; l < 3; ++l) {
        gather_k<<<gather_blocks, 256, 0, stream>>>(row_ptr, csr_src, inv,
                                                    (const unsigned*)hcur, (unsigned*)mean, nN);
        sage_mfma_k<<<gemm_blocks, 256, 0, stream>>>(mean, hcur,
                                                     WT + (size_t)l * 128 * 256,
                                                     bl + (size_t)l * HID,
                                                     outs[l], nN);
        hcur = outs[l];
    }

    pool_seg_k<<<nG, 256, 0, stream>>>((const unsigned*)hcur, batch, pooled, nN);
    bn_stats_k<<<1, HID, 0, stream>>>(pooled, gamma, beta, scale, shift, nG);
    fc_k<<<nG, LATENT, 0, stream>>>(pooled, scale, shift, fcW, fcb, out, nG);
}

// Round 6
// 382.868 us; speedup vs baseline: 3.9250x; 1.1463x over previous
//
#include <hip/hip_runtime.h>
#include <cstdint>
#include <cstddef>

constexpr int HID = 128;
constexpr int LATENT = 64;
constexpr int SCAN_B = 1024;

typedef __attribute__((ext_vector_type(8))) short short8;
typedef __attribute__((ext_vector_type(4))) float f32x4;

__device__ inline unsigned short f2bf(float f) {
    unsigned u = __float_as_uint(f);
    u += 0x7fff + ((u >> 16) & 1);          // RNE
    return (unsigned short)(u >> 16);
}
__device__ inline unsigned pack_bf16x2(float lo, float hi) {
    unsigned ulo = __float_as_uint(lo);
    unsigned uhi = __float_as_uint(hi);
    ulo += 0x7fff + ((ulo >> 16) & 1);
    uhi += 0x7fff + ((uhi >> 16) & 1);
    return (ulo >> 16) | (uhi & 0xffff0000u);
}

// ---------------- CSR build: histogram of dst ----------------
__global__ __launch_bounds__(256) void hist_k(const int* __restrict__ dst,
                                              int* __restrict__ hist, int nE) {
    int i = blockIdx.x * 256 + threadIdx.x;
    if (i < nE) atomicAdd(&hist[dst[i]], 1);
}

// ---------------- 3-phase device-wide exclusive scan ----------------
__global__ __launch_bounds__(SCAN_B) void scan_blocksums_k(const int* __restrict__ hist,
                                                           int* __restrict__ blockSums, int nN) {
    __shared__ int red[SCAN_B / 64];
    int i = blockIdx.x * SCAN_B + threadIdx.x;
    int v = (i < nN) ? hist[i] : 0;
    #pragma unroll
    for (int d = 1; d < 64; d <<= 1) v += __shfl_down(v, d, 64);
    int wave = threadIdx.x >> 6, lane = threadIdx.x & 63;
    if (lane == 0) red[wave] = v;
    __syncthreads();
    if (threadIdx.x == 0) {
        int s = 0;
        #pragma unroll
        for (int w = 0; w < SCAN_B / 64; ++w) s += red[w];
        blockSums[blockIdx.x] = s;
    }
}

__global__ __launch_bounds__(64) void scan_offsets_k(int* __restrict__ blockSums, int nB) {
    int lane = threadIdx.x;
    int v = (lane < nB) ? blockSums[lane] : 0;
    int incl = v;
    #pragma unroll
    for (int d = 1; d < 64; d <<= 1) {
        int u = __shfl_up(incl, d, 64);
        if (lane >= d) incl += u;
    }
    if (lane < nB) blockSums[lane] = incl - v;
}

__global__ __launch_bounds__(SCAN_B) void scan_write_k(const int* __restrict__ hist,
                                                       const int* __restrict__ blockSums,
                                                       int* __restrict__ row_ptr,
                                                       int* __restrict__ offset,
                                                       float* __restrict__ inv,
                                                       int nN, int nE) {
    __shared__ int part[SCAN_B];
    int t = threadIdx.x;
    int i = blockIdx.x * SCAN_B + t;
    int c = (i < nN) ? hist[i] : 0;
    part[t] = c;
    __syncthreads();
    #pragma unroll
    for (int d = 1; d < SCAN_B; d <<= 1) {
        int u = (t >= d) ? part[t - d] : 0;
        __syncthreads();
        if (t >= d) part[t] += u;
        __syncthreads();
    }
    if (i < nN) {
        int excl = blockSums[blockIdx.x] + part[t] - c;
        row_ptr[i] = excl;
        offset[i]  = excl;
        inv[i] = 1.0f / fmaxf((float)c, 1.0f);
    }
    if (blockIdx.x == 0 && t == 0) row_ptr[nN] = nE;
}

// ---------------- permutation scatter: bucket src ids by dst ----------------
__global__ __launch_bounds__(256) void perm_k(const int* __restrict__ src,
                                              const int* __restrict__ dst,
                                              int* __restrict__ offset,
                                              int* __restrict__ csr_src, int nE) {
    int i = blockIdx.x * 256 + threadIdx.x;
    if (i < nE) {
        int pos = atomicAdd(&offset[dst[i]], 1);
        csr_src[pos] = src[i];
    }
}

// ---------------- f32 -> bf16 conversion (x input, once) ----------------
__global__ __launch_bounds__(256) void tobf16_k(const float* __restrict__ in,
                                                unsigned* __restrict__ out, int n2) {
    int i = blockIdx.x * 256 + threadIdx.x;
    if (i < n2) {
        float2 v = ((const float2*)in)[i];
        out[i] = pack_bf16x2(v.x, v.y);
    }
}

// ---------------- weight conversion: WT[l][n][k] bf16, k in [0,256) ----------------
__global__ __launch_bounds__(256) void convW_k(const float* __restrict__ Wl,
                                               const float* __restrict__ Wr,
                                               unsigned short* __restrict__ WT) {
    int idx = blockIdx.x * 256 + threadIdx.x;
    if (idx >= 3 * 128 * 256) return;
    int l = idx / (128 * 256);
    int rem = idx % (128 * 256);
    int n = rem / 256;
    int k = rem % 256;
    float v = (k < 128) ? Wl[(size_t)l * 128 * 128 + (size_t)k * 128 + n]
                        : Wr[(size_t)l * 128 * 128 + (size_t)(k - 128) * 128 + n];
    WT[idx] = f2bf(v);
}

// ---------------- pull-gather mean aggregation, index-broadcast + 4x ILP ----------------
__global__ __launch_bounds__(256) void gather_k(const int* __restrict__ row_ptr,
                                                const int* __restrict__ csr_src,
                                                const float* __restrict__ inv,
                                                const unsigned* __restrict__ h2,
                                                unsigned* __restrict__ mean2, int nN) {
    int w = blockIdx.x * 4 + (threadIdx.x >> 6);
    if (w >= nN) return;
    int lane = threadIdx.x & 63;
    int beg = row_ptr[w], end = row_ptr[w + 1];
    float a0 = 0.f, a1 = 0.f, b0 = 0.f, b1 = 0.f;
    float c0 = 0.f, c1 = 0.f, d0 = 0.f, d1 = 0.f;
    for (int base = beg; base < end; base += 64) {
        int n = min(64, end - base);
        int idx = (lane < n) ? csr_src[base + lane] : 0;
        int j = 0;
        for (; j + 4 <= n; j += 4) {
            int s0 = __shfl(idx, j, 64);
            int s1 = __shfl(idx, j + 1, 64);
            int s2 = __shfl(idx, j + 2, 64);
            int s3 = __shfl(idx, j + 3, 64);
            unsigned u0 = h2[(size_t)s0 * 64 + lane];
            unsigned u1 = h2[(size_t)s1 * 64 + lane];
            unsigned u2 = h2[(size_t)s2 * 64 + lane];
            unsigned u3 = h2[(size_t)s3 * 64 + lane];
            a0 += __uint_as_float(u0 << 16); a1 += __uint_as_float(u0 & 0xffff0000u);
            b0 += __uint_as_float(u1 << 16); b1 += __uint_as_float(u1 & 0xffff0000u);
            c0 += __uint_as_float(u2 << 16); c1 += __uint_as_float(u2 & 0xffff0000u);
            d0 += __uint_as_float(u3 << 16); d1 += __uint_as_float(u3 & 0xffff0000u);
        }
        for (; j < n; ++j) {
            int s0 = __shfl(idx, j, 64);
            unsigned u0 = h2[(size_t)s0 * 64 + lane];
            a0 += __uint_as_float(u0 << 16); a1 += __uint_as_float(u0 & 0xffff0000u);
        }
    }
    float iv = inv[w];
    mean2[(size_t)w * 64 + lane] = pack_bf16x2((a0 + b0 + c0 + d0) * iv,
                                               (a1 + b1 + c1 + d1) * iv);
}

// ---------------- MFMA SAGE transform: out = relu([mean|h] @ WT^T + bl), bf16 ----------------
__global__ __launch_bounds__(256) void sage_mfma_k(
    const unsigned short* __restrict__ mean,
    const unsigned short* __restrict__ h,
    const unsigned short* __restrict__ WT,   // [128][256] bf16
    const float* __restrict__ bl,
    unsigned short* __restrict__ out, int nN)
{
    __shared__ unsigned short sB[128 * 256];   // exactly 64 KB

    {
        int row = threadIdx.x >> 1, half = threadIdx.x & 1;
        const short8* src = (const short8*)(WT + row * 256 + half * 128);
        int sw = (row & 7) << 2;
        #pragma unroll
        for (int j = 0; j < 16; ++j) {
            int unit = half * 16 + j;
            int unit2 = unit ^ sw;
            *(short8*)(sB + row * 256 + unit2 * 8) = src[j];
        }
    }
    __syncthreads();

    const int wave = threadIdx.x >> 6;
    const int lane = threadIdx.x & 63;
    const int m = lane & 15;
    const int q = lane >> 4;
    const int row = blockIdx.x * 64 + wave * 16 + m;
    const int rowc = min(row, nN - 1);
    const int swm = (m & 7) << 2;

    f32x4 acc[8] = {};
    #pragma unroll
    for (int ks = 0; ks < 8; ++ks) {
        const unsigned short* Aptr = (ks < 4) ? mean : h;
        short8 a = *(const short8*)(Aptr + (size_t)rowc * HID + (ks & 3) * 32 + q * 8);
        #pragma unroll
        for (int t = 0; t < 8; ++t) {
            int unit2 = (ks * 4 + q) ^ swm;
            short8 b = *(const short8*)(sB + (t * 16 + m) * 256 + unit2 * 8);
            acc[t] = __builtin_amdgcn_mfma_f32_16x16x32_bf16(a, b, acc[t], 0, 0, 0);
        }
    }

    int orow_base = blockIdx.x * 64 + wave * 16 + q * 4;
    #pragma unroll
    for (int t = 0; t < 8; ++t) {
        float bias = bl[t * 16 + m];
        #pragma unroll
        for (int r = 0; r < 4; ++r) {
            int orow = orow_base + r;
            if (orow < nN) {
                float v = fmaxf(acc[t][r] + bias, 0.f);
                out[(size_t)orow * HID + t * 16 + m] = f2bf(v);
            }
        }
    }
}

// ---------------- segmented pool (batch sorted): one block per graph ----------------
__global__ __launch_bounds__(256) void pool_seg_k(const unsigned* __restrict__ h2,
                                                  const int* __restrict__ batch,
                                                  float* __restrict__ pooled, int nN) {
    int g = blockIdx.x;
    int lo = 0, hi = nN;
    while (lo < hi) { int mid = (lo + hi) >> 1; if (batch[mid] < g) lo = mid + 1; else hi = mid; }
    int beg = lo;
    hi = nN;
    while (lo < hi) { int mid = (lo + hi) >> 1; if (batch[mid] <= g) lo = mid + 1; else hi = mid; }
    int end = lo;

    int lane = threadIdx.x & 63;
    int sub  = threadIdx.x >> 6;          // 4 waves
    float s0 = 0.f, s1 = 0.f;
    for (int i = beg + sub; i < end; i += 4) {
        unsigned u = h2[(size_t)i * 64 + lane];
        s0 += __uint_as_float(u << 16);
        s1 += __uint_as_float(u & 0xffff0000u);
    }
    __shared__ float red[4][HID];
    red[sub][2 * lane]     = s0;
    red[sub][2 * lane + 1] = s1;
    __syncthreads();
    if (sub == 0) {
        float v0 = red[0][2 * lane] + red[1][2 * lane] + red[2][2 * lane] + red[3][2 * lane];
        float v1 = red[0][2 * lane + 1] + red[1][2 * lane + 1] + red[2][2 * lane + 1] + red[3][2 * lane + 1];
        pooled[(size_t)g * HID + 2 * lane]     = v0;
        pooled[(size_t)g * HID + 2 * lane + 1] = v1;
    }
}

// ---------------- batchnorm stats: 1024 thr, 8 graph-stripes x 128 features ----------------
__global__ __launch_bounds__(1024) void bn_stats_k(const float* __restrict__ pooled,
                                                   const float* __restrict__ gamma,
                                                   const float* __restrict__ beta,
                                                   float* __restrict__ scale,
                                                   float* __restrict__ shift, int nG) {
    __shared__ float rs[8][HID], rs2[8][HID];
    int j = threadIdx.x & (HID - 1);
    int stripe = threadIdx.x >> 7;         // 0..7
    float s = 0.f, s2 = 0.f;
    for (int g = stripe; g < nG; g += 8) { // coalesced 4 KB per step, independent loads
        float v = pooled[(size_t)g * HID + j];
        s += v; s2 += v * v;
    }
    rs[stripe][j] = s; rs2[stripe][j] = s2;
    __syncthreads();
    if (threadIdx.x < HID) {
        float S = 0.f, S2 = 0.f;
        #pragma unroll
        for (int k = 0; k < 8; ++k) { S += rs[k][j]; S2 += rs2[k][j]; }
        float invG = 1.0f / (float)nG;
        float mu = S * invG;
        float var = S2 * invG - mu * mu;
        float r = rsqrtf(var + 1e-5f) * gamma[j];
        scale[j] = r;
        shift[j] = beta[j] - mu * r;
    }
}

// ---------------- final FC ----------------
__global__ __launch_bounds__(LATENT) void fc_k(const float* __restrict__ pooled,
                                               const float* __restrict__ scale,
                                               const float* __restrict__ shift,
                                               const float* __restrict__ fcW,
                                               const float* __restrict__ fcb,
                                               float* __restrict__ out, int nG) {
    int g = blockIdx.x;
    int o = threadIdx.x;
    float acc = fcb[o];
    for (int j = 0; j < HID; ++j) {
        float v = pooled[(size_t)g * HID + j] * scale[j] + shift[j];
        acc += v * fcW[(size_t)j * LATENT + o];
    }
    out[(size_t)g * LATENT + o] = acc;
}

extern "C" void kernel_launch(void* const* d_in, const int* in_sizes, int n_in,
                              void* d_out, int out_size, void* d_ws, size_t ws_size,
                              hipStream_t stream) {
    const float* x     = (const float*)d_in[0];
    const int*   ei    = (const int*)d_in[1];
    const int*   batch = (const int*)d_in[2];
    const float* Wl    = (const float*)d_in[3];
    const float* bl    = (const float*)d_in[4];
    const float* Wr    = (const float*)d_in[5];
    const float* gamma = (const float*)d_in[6];
    const float* beta  = (const float*)d_in[7];
    const float* fcW   = (const float*)d_in[8];
    const float* fcb   = (const float*)d_in[9];
    float* out = (float*)d_out;

    const int nN = in_sizes[0] / HID;      // 50000
    const int nE = in_sizes[1] / 2;        // 800000
    const int nG = out_size / LATENT;      // 256
    const int* src = ei;
    const int* dst = ei + nE;

    unsigned short* hx   = (unsigned short*)d_ws;           // nN*HID bf16
    unsigned short* B1   = hx + (size_t)nN * HID;
    unsigned short* B2   = B1 + (size_t)nN * HID;
    unsigned short* mean = B2 + (size_t)nN * HID;
    unsigned short* WT   = mean + (size_t)nN * HID;         // 3*128*256 bf16
    float* inv    = (float*)(WT + 3 * 128 * 256);
    float* pooled = inv + nN;
    float* scale  = pooled + (size_t)nG * HID;
    float* shift  = scale + HID;
    int*   hist      = (int*)(shift + HID);
    int*   row_ptr   = hist + nN;
    int*   offset    = row_ptr + (nN + 1);
    int*   csr_src   = offset + nN;
    int*   blockSums = csr_src + nE;

    const int nB = (nN + SCAN_B - 1) / SCAN_B;

    // ---- CSR build ----
    hipMemsetAsync(hist, 0, (size_t)nN * sizeof(int), stream);
    hist_k<<<(nE + 255) / 256, 256, 0, stream>>>(dst, hist, nE);
    scan_blocksums_k<<<nB, SCAN_B, 0, stream>>>(hist, blockSums, nN);
    scan_offsets_k<<<1, 64, 0, stream>>>(blockSums, nB);
    scan_write_k<<<nB, SCAN_B, 0, stream>>>(hist, blockSums, row_ptr, offset, inv, nN, nE);
    perm_k<<<(nE + 255) / 256, 256, 0, stream>>>(src, dst, offset, csr_src, nE);

    // ---- precompute bf16 buffers ----
    tobf16_k<<<((nN * HID / 2) + 255) / 256, 256, 0, stream>>>(x, (unsigned*)hx, nN * HID / 2);
    convW_k<<<(3 * 128 * 256 + 255) / 256, 256, 0, stream>>>(Wl, Wr, WT);

    const int gather_blocks = (nN + 3) / 4;
    const int gemm_blocks = (nN + 63) / 64;

    const unsigned short* hcur = hx;
    unsigned short* outs[3] = {B1, B2, B1};
    for (int l = 0; l < 3; ++l) {
        gather_k<<<gather_blocks, 256, 0, stream>>>(row_ptr, csr_src, inv,
                                                    (const unsigned*)hcur, (unsigned*)mean, nN);
        sage_mfma_k<<<gemm_blocks, 256, 0, stream>>>(mean, hcur,
                                                     WT + (size_t)l * 128 * 256,
                                                     bl + (size_t)l * HID,
                                                     outs[l], nN);
        hcur = outs[l];
    }

    pool_seg_k<<<nG, 256, 0, stream>>>((const unsigned*)hcur, batch, pooled, nN);
    bn_stats_k<<<1, 1024, 0, stream>>>(pooled, gamma, beta, scale, shift, nG);
    fc_k<<<nG, LATENT, 0, stream>>>(pooled, scale, shift, fcW, fcb, out, nG);
}

// Round 7
// 376.252 us; speedup vs baseline: 3.9940x; 1.0176x over previous
//
#include <hip/hip_runtime.h>
#include <cstdint>
#include <cstddef>

constexpr int HID = 128;
constexpr int LATENT = 64;
constexpr int SCAN_B = 1024;

typedef __attribute__((ext_vector_type(8))) short short8;
typedef __attribute__((ext_vector_type(4))) float f32x4;

__device__ inline unsigned short f2bf(float f) {
    unsigned u = __float_as_uint(f);
    u += 0x7fff + ((u >> 16) & 1);          // RNE
    return (unsigned short)(u >> 16);
}
__device__ inline unsigned pack_bf16x2(float lo, float hi) {
    unsigned ulo = __float_as_uint(lo);
    unsigned uhi = __float_as_uint(hi);
    ulo += 0x7fff + ((ulo >> 16) & 1);
    uhi += 0x7fff + ((uhi >> 16) & 1);
    return (ulo >> 16) | (uhi & 0xffff0000u);
}

// ---------------- CSR build: histogram of dst ----------------
__global__ __launch_bounds__(256) void hist_k(const int* __restrict__ dst,
                                              int* __restrict__ hist, int nE) {
    int i = blockIdx.x * 256 + threadIdx.x;
    if (i < nE) atomicAdd(&hist[dst[i]], 1);
}

// ---------------- 3-phase device-wide exclusive scan ----------------
__global__ __launch_bounds__(SCAN_B) void scan_blocksums_k(const int* __restrict__ hist,
                                                           int* __restrict__ blockSums, int nN) {
    __shared__ int red[SCAN_B / 64];
    int i = blockIdx.x * SCAN_B + threadIdx.x;
    int v = (i < nN) ? hist[i] : 0;
    #pragma unroll
    for (int d = 1; d < 64; d <<= 1) v += __shfl_down(v, d, 64);
    int wave = threadIdx.x >> 6, lane = threadIdx.x & 63;
    if (lane == 0) red[wave] = v;
    __syncthreads();
    if (threadIdx.x == 0) {
        int s = 0;
        #pragma unroll
        for (int w = 0; w < SCAN_B / 64; ++w) s += red[w];
        blockSums[blockIdx.x] = s;
    }
}

__global__ __launch_bounds__(64) void scan_offsets_k(int* __restrict__ blockSums, int nB) {
    int lane = threadIdx.x;
    int v = (lane < nB) ? blockSums[lane] : 0;
    int incl = v;
    #pragma unroll
    for (int d = 1; d < 64; d <<= 1) {
        int u = __shfl_up(incl, d, 64);
        if (lane >= d) incl += u;
    }
    if (lane < nB) blockSums[lane] = incl - v;
}

__global__ __launch_bounds__(SCAN_B) void scan_write_k(const int* __restrict__ hist,
                                                       const int* __restrict__ blockSums,
                                                       int* __restrict__ row_ptr,
                                                       int* __restrict__ offset,
                                                       float* __restrict__ inv,
                                                       int nN, int nE) {
    __shared__ int part[SCAN_B];
    int t = threadIdx.x;
    int i = blockIdx.x * SCAN_B + t;
    int c = (i < nN) ? hist[i] : 0;
    part[t] = c;
    __syncthreads();
    #pragma unroll
    for (int d = 1; d < SCAN_B; d <<= 1) {
        int u = (t >= d) ? part[t - d] : 0;
        __syncthreads();
        if (t >= d) part[t] += u;
        __syncthreads();
    }
    if (i < nN) {
        int excl = blockSums[blockIdx.x] + part[t] - c;
        row_ptr[i] = excl;
        offset[i]  = excl;
        inv[i] = 1.0f / fmaxf((float)c, 1.0f);
    }
    if (blockIdx.x == 0 && t == 0) row_ptr[nN] = nE;
}

// ---------------- permutation scatter: bucket src ids by dst ----------------
__global__ __launch_bounds__(256) void perm_k(const int* __restrict__ src,
                                              const int* __restrict__ dst,
                                              int* __restrict__ offset,
                                              int* __restrict__ csr_src, int nE) {
    int i = blockIdx.x * 256 + threadIdx.x;
    if (i < nE) {
        int pos = atomicAdd(&offset[dst[i]], 1);
        csr_src[pos] = src[i];
    }
}

// ---------------- f32 -> bf16 conversion (x input, once) ----------------
__global__ __launch_bounds__(256) void tobf16_k(const float* __restrict__ in,
                                                unsigned* __restrict__ out, int n2) {
    int i = blockIdx.x * 256 + threadIdx.x;
    if (i < n2) {
        float2 v = ((const float2*)in)[i];
        out[i] = pack_bf16x2(v.x, v.y);
    }
}

// ---------------- weight conversion: WT[l][n][k] bf16, k in [0,256) ----------------
__global__ __launch_bounds__(256) void convW_k(const float* __restrict__ Wl,
                                               const float* __restrict__ Wr,
                                               unsigned short* __restrict__ WT) {
    int idx = blockIdx.x * 256 + threadIdx.x;
    if (idx >= 3 * 128 * 256) return;
    int l = idx / (128 * 256);
    int rem = idx % (128 * 256);
    int n = rem / 256;
    int k = rem % 256;
    float v = (k < 128) ? Wl[(size_t)l * 128 * 128 + (size_t)k * 128 + n]
                        : Wr[(size_t)l * 128 * 128 + (size_t)(k - 128) * 128 + n];
    WT[idx] = f2bf(v);
}

// ---------------- pull-gather mean aggregation: uint4 loads, 16 lanes/row ----------------
// One wave per node. quarter q=lane>>4 handles edge (j+q); col=lane&15 is the
// 16B chunk of the 256B row. 8 edges per iteration (2 independent loads/lane).
__global__ __launch_bounds__(256) void gather_k(const int* __restrict__ row_ptr,
                                                const int* __restrict__ csr_src,
                                                const float* __restrict__ inv,
                                                const uint4* __restrict__ h4,
                                                uint4* __restrict__ mean4, int nN) {
    int w = blockIdx.x * 4 + (threadIdx.x >> 6);
    if (w >= nN) return;
    int lane = threadIdx.x & 63;
    int quarter = lane >> 4;
    int col = lane & 15;
    int beg = row_ptr[w], end = row_ptr[w + 1];
    float accA[8] = {}, accB[8] = {};
    for (int base = beg; base < end; base += 64) {
        int navail = min(64, end - base);
        int idx = (lane < navail) ? csr_src[base + lane] : 0;
        for (int j = 0; j < navail; j += 8) {
            int e0 = j + quarter;
            int e1 = j + 4 + quarter;
            int s0 = __shfl(idx, min(e0, navail - 1), 64);
            int s1 = __shfl(idx, min(e1, navail - 1), 64);
            uint4 u0 = h4[(size_t)s0 * 16 + col];
            uint4 u1 = h4[(size_t)s1 * 16 + col];
            if (e0 < navail) {
                accA[0] += __uint_as_float(u0.x << 16); accA[1] += __uint_as_float(u0.x & 0xffff0000u);
                accA[2] += __uint_as_float(u0.y << 16); accA[3] += __uint_as_float(u0.y & 0xffff0000u);
                accA[4] += __uint_as_float(u0.z << 16); accA[5] += __uint_as_float(u0.z & 0xffff0000u);
                accA[6] += __uint_as_float(u0.w << 16); accA[7] += __uint_as_float(u0.w & 0xffff0000u);
            }
            if (e1 < navail) {
                accB[0] += __uint_as_float(u1.x << 16); accB[1] += __uint_as_float(u1.x & 0xffff0000u);
                accB[2] += __uint_as_float(u1.y << 16); accB[3] += __uint_as_float(u1.y & 0xffff0000u);
                accB[4] += __uint_as_float(u1.z << 16); accB[5] += __uint_as_float(u1.z & 0xffff0000u);
                accB[6] += __uint_as_float(u1.w << 16); accB[7] += __uint_as_float(u1.w & 0xffff0000u);
            }
        }
    }
    // combine edge-pair accs, then reduce across quarters (xor 16, xor 32)
    #pragma unroll
    for (int k = 0; k < 8; ++k) {
        float v = accA[k] + accB[k];
        v += __shfl_xor(v, 16, 64);
        v += __shfl_xor(v, 32, 64);
        accA[k] = v;
    }
    if (quarter == 0) {
        float iv = inv[w];
        uint4 o;
        o.x = pack_bf16x2(accA[0] * iv, accA[1] * iv);
        o.y = pack_bf16x2(accA[2] * iv, accA[3] * iv);
        o.z = pack_bf16x2(accA[4] * iv, accA[5] * iv);
        o.w = pack_bf16x2(accA[6] * iv, accA[7] * iv);
        mean4[(size_t)w * 16 + col] = o;
    }
}

// ---------------- MFMA SAGE transform: out = relu([mean|h] @ WT^T + bl), bf16 ----------------
__global__ __launch_bounds__(256) void sage_mfma_k(
    const unsigned short* __restrict__ mean,
    const unsigned short* __restrict__ h,
    const unsigned short* __restrict__ WT,   // [128][256] bf16
    const float* __restrict__ bl,
    unsigned short* __restrict__ out, int nN)
{
    __shared__ unsigned short sB[128 * 256];   // exactly 64 KB

    {
        int row = threadIdx.x >> 1, half = threadIdx.x & 1;
        const short8* src = (const short8*)(WT + row * 256 + half * 128);
        int sw = (row & 7) << 2;
        #pragma unroll
        for (int j = 0; j < 16; ++j) {
            int unit = half * 16 + j;
            int unit2 = unit ^ sw;
            *(short8*)(sB + row * 256 + unit2 * 8) = src[j];
        }
    }
    __syncthreads();

    const int wave = threadIdx.x >> 6;
    const int lane = threadIdx.x & 63;
    const int m = lane & 15;
    const int q = lane >> 4;
    const int row = blockIdx.x * 64 + wave * 16 + m;
    const int rowc = min(row, nN - 1);
    const int swm = (m & 7) << 2;

    f32x4 acc[8] = {};
    #pragma unroll
    for (int ks = 0; ks < 8; ++ks) {
        const unsigned short* Aptr = (ks < 4) ? mean : h;
        short8 a = *(const short8*)(Aptr + (size_t)rowc * HID + (ks & 3) * 32 + q * 8);
        #pragma unroll
        for (int t = 0; t < 8; ++t) {
            int unit2 = (ks * 4 + q) ^ swm;
            short8 b = *(const short8*)(sB + (t * 16 + m) * 256 + unit2 * 8);
            acc[t] = __builtin_amdgcn_mfma_f32_16x16x32_bf16(a, b, acc[t], 0, 0, 0);
        }
    }

    int orow_base = blockIdx.x * 64 + wave * 16 + q * 4;
    #pragma unroll
    for (int t = 0; t < 8; ++t) {
        float bias = bl[t * 16 + m];
        #pragma unroll
        for (int r = 0; r < 4; ++r) {
            int orow = orow_base + r;
            if (orow < nN) {
                float v = fmaxf(acc[t][r] + bias, 0.f);
                out[(size_t)orow * HID + t * 16 + m] = f2bf(v);
            }
        }
    }
}

// ---------------- segmented pool (batch sorted): one block per graph ----------------
__global__ __launch_bounds__(256) void pool_seg_k(const unsigned* __restrict__ h2,
                                                  const int* __restrict__ batch,
                                                  float* __restrict__ pooled, int nN) {
    int g = blockIdx.x;
    int lo = 0, hi = nN;
    while (lo < hi) { int mid = (lo + hi) >> 1; if (batch[mid] < g) lo = mid + 1; else hi = mid; }
    int beg = lo;
    hi = nN;
    while (lo < hi) { int mid = (lo + hi) >> 1; if (batch[mid] <= g) lo = mid + 1; else hi = mid; }
    int end = lo;

    int lane = threadIdx.x & 63;
    int sub  = threadIdx.x >> 6;          // 4 waves
    float s0 = 0.f, s1 = 0.f;
    for (int i = beg + sub; i < end; i += 4) {
        unsigned u = h2[(size_t)i * 64 + lane];
        s0 += __uint_as_float(u << 16);
        s1 += __uint_as_float(u & 0xffff0000u);
    }
    __shared__ float red[4][HID];
    red[sub][2 * lane]     = s0;
    red[sub][2 * lane + 1] = s1;
    __syncthreads();
    if (sub == 0) {
        float v0 = red[0][2 * lane] + red[1][2 * lane] + red[2][2 * lane] + red[3][2 * lane];
        float v1 = red[0][2 * lane + 1] + red[1][2 * lane + 1] + red[2][2 * lane + 1] + red[3][2 * lane + 1];
        pooled[(size_t)g * HID + 2 * lane]     = v0;
        pooled[(size_t)g * HID + 2 * lane + 1] = v1;
    }
}

// ---------------- batchnorm stats: 1024 thr, 8 graph-stripes x 128 features ----------------
__global__ __launch_bounds__(1024) void bn_stats_k(const float* __restrict__ pooled,
                                                   const float* __restrict__ gamma,
                                                   const float* __restrict__ beta,
                                                   float* __restrict__ scale,
                                                   float* __restrict__ shift, int nG) {
    __shared__ float rs[8][HID], rs2[8][HID];
    int j = threadIdx.x & (HID - 1);
    int stripe = threadIdx.x >> 7;         // 0..7
    float s = 0.f, s2 = 0.f;
    for (int g = stripe; g < nG; g += 8) {
        float v = pooled[(size_t)g * HID + j];
        s += v; s2 += v * v;
    }
    rs[stripe][j] = s; rs2[stripe][j] = s2;
    __syncthreads();
    if (threadIdx.x < HID) {
        float S = 0.f, S2 = 0.f;
        #pragma unroll
        for (int k = 0; k < 8; ++k) { S += rs[k][j]; S2 += rs2[k][j]; }
        float invG = 1.0f / (float)nG;
        float mu = S * invG;
        float var = S2 * invG - mu * mu;
        float r = rsqrtf(var + 1e-5f) * gamma[j];
        scale[j] = r;
        shift[j] = beta[j] - mu * r;
    }
}

// ---------------- final FC ----------------
__global__ __launch_bounds__(LATENT) void fc_k(const float* __restrict__ pooled,
                                               const float* __restrict__ scale,
                                               const float* __restrict__ shift,
                                               const float* __restrict__ fcW,
                                               const float* __restrict__ fcb,
                                               float* __restrict__ out, int nG) {
    int g = blockIdx.x;
    int o = threadIdx.x;
    float acc = fcb[o];
    for (int j = 0; j < HID; ++j) {
        float v = pooled[(size_t)g * HID + j] * scale[j] + shift[j];
        acc += v * fcW[(size_t)j * LATENT + o];
    }
    out[(size_t)g * LATENT + o] = acc;
}

extern "C" void kernel_launch(void* const* d_in, const int* in_sizes, int n_in,
                              void* d_out, int out_size, void* d_ws, size_t ws_size,
                              hipStream_t stream) {
    const float* x     = (const float*)d_in[0];
    const int*   ei    = (const int*)d_in[1];
    const int*   batch = (const int*)d_in[2];
    const float* Wl    = (const float*)d_in[3];
    const float* bl    = (const float*)d_in[4];
    const float* Wr    = (const float*)d_in[5];
    const float* gamma = (const float*)d_in[6];
    const float* beta  = (const float*)d_in[7];
    const float* fcW   = (const float*)d_in[8];
    const float* fcb   = (const float*)d_in[9];
    float* out = (float*)d_out;

    const int nN = in_sizes[0] / HID;      // 50000
    const int nE = in_sizes[1] / 2;        // 800000
    const int nG = out_size / LATENT;      // 256
    const int* src = ei;
    const int* dst = ei + nE;

    unsigned short* hx   = (unsigned short*)d_ws;           // nN*HID bf16
    unsigned short* B1   = hx + (size_t)nN * HID;
    unsigned short* B2   = B1 + (size_t)nN * HID;
    unsigned short* mean = B2 + (size_t)nN * HID;
    unsigned short* WT   = mean + (size_t)nN * HID;         // 3*128*256 bf16
    float* inv    = (float*)(WT + 3 * 128 * 256);
    float* pooled = inv + nN;
    float* scale  = pooled + (size_t)nG * HID;
    float* shift  = scale + HID;
    int*   hist      = (int*)(shift + HID);
    int*   row_ptr   = hist + nN;
    int*   offset    = row_ptr + (nN + 1);
    int*   csr_src   = offset + nN;
    int*   blockSums = csr_src + nE;

    const int nB = (nN + SCAN_B - 1) / SCAN_B;

    // ---- CSR build ----
    hipMemsetAsync(hist, 0, (size_t)nN * sizeof(int), stream);
    hist_k<<<(nE + 255) / 256, 256, 0, stream>>>(dst, hist, nE);
    scan_blocksums_k<<<nB, SCAN_B, 0, stream>>>(hist, blockSums, nN);
    scan_offsets_k<<<1, 64, 0, stream>>>(blockSums, nB);
    scan_write_k<<<nB, SCAN_B, 0, stream>>>(hist, blockSums, row_ptr, offset, inv, nN, nE);
    perm_k<<<(nE + 255) / 256, 256, 0, stream>>>(src, dst, offset, csr_src, nE);

    // ---- precompute bf16 buffers ----
    tobf16_k<<<((nN * HID / 2) + 255) / 256, 256, 0, stream>>>(x, (unsigned*)hx, nN * HID / 2);
    convW_k<<<(3 * 128 * 256 + 255) / 256, 256, 0, stream>>>(Wl, Wr, WT);

    const int gather_blocks = (nN + 3) / 4;
    const int gemm_blocks = (nN + 63) / 64;

    const unsigned short* hcur = hx;
    unsigned short* outs[3] = {B1, B2, B1};
    for (int l = 0; l < 3; ++l) {
        gather_k<<<gather_blocks, 256, 0, stream>>>(row_ptr, csr_src, inv,
                                                    (const uint4*)hcur, (uint4*)mean, nN);
        sage_mfma_k<<<gemm_blocks, 256, 0, stream>>>(mean, hcur,
                                                     WT + (size_t)l * 128 * 256,
                                                     bl + (size_t)l * HID,
                                                     outs[l], nN);
        hcur = outs[l];
    }

    pool_seg_k<<<nG, 256, 0, stream>>>((const unsigned*)hcur, batch, pooled, nN);
    bn_stats_k<<<1, 1024, 0, stream>>>(pooled, gamma, beta, scale, shift, nG);
    fc_k<<<nG, LATENT, 0, stream>>>(pooled, scale, shift, fcW, fcb, out, nG);
}